// Round 1
// baseline (765.677 us; speedup 1.0000x reference)
//
#include <hip/hip_runtime.h>
#include <hip/hip_bf16.h>

#define DEV __device__ __forceinline__

typedef __attribute__((ext_vector_type(8))) short short8;
typedef __attribute__((ext_vector_type(4))) float f32x4;

constexpr int Bb   = 4;
constexpr int SEQ  = 2048;
constexpr int C    = 1024;
constexpr int HID  = 4096;
constexpr int NH   = 16;
constexpr int HD   = 64;
constexpr int MTOT = Bb * SEQ;   // 8192 tokens

DEV short f2bf(float f) {
  unsigned x = __float_as_uint(f);
  x = (x + 0x7fffu + ((x >> 16) & 1u)) >> 16;   // RNE to bf16
  return (short)x;
}

// ---------------- weight transpose: fp32 [R][Cc] -> bf16 [Cc][R] ----------------
__global__ void k_transpose_w(const float* __restrict__ src, short* __restrict__ dst,
                              int R, int Cc) {
  __shared__ float t[32][33];
  int tx = threadIdx.x & 31, ty = threadIdx.x >> 5;   // 32 x 8
  int c0 = blockIdx.x * 32, r0 = blockIdx.y * 32;
  #pragma unroll
  for (int i = 0; i < 4; i++)
    t[ty + i * 8][tx] = src[(size_t)(r0 + ty + i * 8) * Cc + c0 + tx];
  __syncthreads();
  #pragma unroll
  for (int i = 0; i < 4; i++)
    dst[(size_t)(c0 + ty + i * 8) * R + r0 + tx] = f2bf(t[tx][ty + i * 8]);
}

// ---------------- V transpose: bf16 [tok][C] -> per-(b,h) [HD][SEQ] ----------------
__global__ void k_transpose_v(const short* __restrict__ V, short* __restrict__ Vt) {
  __shared__ short t[32][33];
  int tx = threadIdx.x & 31, ty = threadIdx.x >> 5;
  int plane = blockIdx.z;                 // b*16 + h
  int b = plane >> 4, h = plane & 15;
  int n0 = blockIdx.x * 32, d0 = blockIdx.y * 32;
  #pragma unroll
  for (int i = 0; i < 4; i++)
    t[ty + i * 8][tx] = V[(size_t)(b * SEQ + n0 + ty + i * 8) * C + h * HD + d0 + tx];
  __syncthreads();
  #pragma unroll
  for (int i = 0; i < 4; i++)
    Vt[((size_t)plane * HD + d0 + ty + i * 8) * SEQ + n0 + tx] = t[tx][ty + i * 8];
}

// ---------------- fused LN for q-input (x) and kv-input (x+pos) ----------------
__global__ void k_ln_qkv(const float* __restrict__ x, const float* __restrict__ pos,
                         const float* __restrict__ nqg, const float* __restrict__ nqb,
                         const float* __restrict__ nkg, const float* __restrict__ nkb,
                         const float* __restrict__ nvg, const float* __restrict__ nvb,
                         short* __restrict__ xq, short* __restrict__ xk,
                         short* __restrict__ xv) {
  int row = blockIdx.x, tid = threadIdx.x;
  int n = row & (SEQ - 1);
  float a4[4], p4[4];
  float s1 = 0, s2 = 0, t1 = 0, t2 = 0;
  #pragma unroll
  for (int i = 0; i < 4; i++) {
    int c = tid + i * 256;
    float a = x[(size_t)row * C + c];
    float p = pos[(size_t)n * C + c] + a;
    a4[i] = a; p4[i] = p;
    s1 += a; s2 += a * a; t1 += p; t2 += p * p;
  }
  #pragma unroll
  for (int off = 32; off; off >>= 1) {
    s1 += __shfl_xor(s1, off, 64);
    s2 += __shfl_xor(s2, off, 64);
    t1 += __shfl_xor(t1, off, 64);
    t2 += __shfl_xor(t2, off, 64);
  }
  __shared__ float red[4][4];
  int wave = tid >> 6, lane = tid & 63;
  if (lane == 0) { red[wave][0] = s1; red[wave][1] = s2; red[wave][2] = t1; red[wave][3] = t2; }
  __syncthreads();
  s1 = red[0][0] + red[1][0] + red[2][0] + red[3][0];
  s2 = red[0][1] + red[1][1] + red[2][1] + red[3][1];
  t1 = red[0][2] + red[1][2] + red[2][2] + red[3][2];
  t2 = red[0][3] + red[1][3] + red[2][3] + red[3][3];
  float mq = s1 * (1.f / C), mk = t1 * (1.f / C);
  float rq = rsqrtf(s2 * (1.f / C) - mq * mq + 1e-5f);
  float rk = rsqrtf(t2 * (1.f / C) - mk * mk + 1e-5f);
  #pragma unroll
  for (int i = 0; i < 4; i++) {
    int c = tid + i * 256;
    float nq_ = (a4[i] - mq) * rq;
    float nk_ = (p4[i] - mk) * rk;
    xq[(size_t)row * C + c] = f2bf(nq_ * nqg[c] + nqb[c]);
    xk[(size_t)row * C + c] = f2bf(nk_ * nkg[c] + nkb[c]);
    xv[(size_t)row * C + c] = f2bf(nk_ * nvg[c] + nvb[c]);
  }
}

// ---------------- plain LN (h -> bf16) ----------------
__global__ void k_ln1(const float* __restrict__ h, const float* __restrict__ g,
                      const float* __restrict__ bta, short* __restrict__ out) {
  int row = blockIdx.x, tid = threadIdx.x;
  float a4[4];
  float s1 = 0, s2 = 0;
  #pragma unroll
  for (int i = 0; i < 4; i++) {
    int c = tid + i * 256;
    float a = h[(size_t)row * C + c];
    a4[i] = a; s1 += a; s2 += a * a;
  }
  #pragma unroll
  for (int off = 32; off; off >>= 1) {
    s1 += __shfl_xor(s1, off, 64);
    s2 += __shfl_xor(s2, off, 64);
  }
  __shared__ float red[4][2];
  int wave = tid >> 6, lane = tid & 63;
  if (lane == 0) { red[wave][0] = s1; red[wave][1] = s2; }
  __syncthreads();
  s1 = red[0][0] + red[1][0] + red[2][0] + red[3][0];
  s2 = red[0][1] + red[1][1] + red[2][1] + red[3][1];
  float m = s1 * (1.f / C);
  float r = rsqrtf(s2 * (1.f / C) - m * m + 1e-5f);
  #pragma unroll
  for (int i = 0; i < 4; i++) {
    int c = tid + i * 256;
    out[(size_t)row * C + c] = f2bf((a4[i] - m) * r * g[c] + bta[c]);
  }
}

// ---------------- GEMM: C = A[M][K] @ Bt[N][K]^T + bias, epilogue variants ----------------
// MODE 0: +bias -> bf16 out;  MODE 1: +bias, LeakyReLU(0.1) -> bf16;  MODE 2: +bias+resid -> fp32
template <int MODE>
__global__ __launch_bounds__(256, 2)
void k_gemm(const short* __restrict__ A, const short* __restrict__ Bt,
            const float* __restrict__ bias, const float* __restrict__ resid,
            void* __restrict__ outp, int Nn, int Kk) {
  __shared__ short sA[128 * 40];   // +8 pad: 2-way (free) bank pattern for b128 reads
  __shared__ short sB[128 * 40];
  const int tid = threadIdx.x;
  const int n0 = blockIdx.x * 128, m0 = blockIdx.y * 128;
  const int wave = tid >> 6, lane = tid & 63, quad = lane >> 4, l15 = lane & 15;
  const int wm = (wave >> 1) * 64, wn = (wave & 1) * 64;

  const f32x4 fzero = {0.f, 0.f, 0.f, 0.f};
  f32x4 acc[4][4];
  #pragma unroll
  for (int mi = 0; mi < 4; mi++)
    #pragma unroll
    for (int ni = 0; ni < 4; ni++) acc[mi][ni] = fzero;

  for (int k0 = 0; k0 < Kk; k0 += 32) {
    #pragma unroll
    for (int i = 0; i < 2; i++) {
      int idx = tid + i * 256, row = idx >> 2, seg = idx & 3;
      *(int4*)&sA[row * 40 + seg * 8] =
          *(const int4*)(A + (size_t)(m0 + row) * Kk + k0 + seg * 8);
      *(int4*)&sB[row * 40 + seg * 8] =
          *(const int4*)(Bt + (size_t)(n0 + row) * Kk + k0 + seg * 8);
    }
    __syncthreads();
    short8 av[4], bv[4];
    #pragma unroll
    for (int mi = 0; mi < 4; mi++)
      av[mi] = *(const short8*)&sA[(wm + mi * 16 + l15) * 40 + quad * 8];
    #pragma unroll
    for (int ni = 0; ni < 4; ni++)
      bv[ni] = *(const short8*)&sB[(wn + ni * 16 + l15) * 40 + quad * 8];
    #pragma unroll
    for (int mi = 0; mi < 4; mi++)
      #pragma unroll
      for (int ni = 0; ni < 4; ni++)
        acc[mi][ni] = __builtin_amdgcn_mfma_f32_16x16x32_bf16(av[mi], bv[ni], acc[mi][ni], 0, 0, 0);
    __syncthreads();
  }

  float bb[4];
  #pragma unroll
  for (int ni = 0; ni < 4; ni++) bb[ni] = bias[n0 + wn + ni * 16 + l15];

  #pragma unroll
  for (int mi = 0; mi < 4; mi++) {
    #pragma unroll
    for (int ni = 0; ni < 4; ni++) {
      #pragma unroll
      for (int r = 0; r < 4; r++) {
        int row = m0 + wm + mi * 16 + quad * 4 + r;   // C/D layout: row=quad*4+reg
        int col = n0 + wn + ni * 16 + l15;            //             col=lane&15
        float v = acc[mi][ni][r] + bb[ni];
        if constexpr (MODE == 1) v = v >= 0.f ? v : 0.1f * v;
        if constexpr (MODE == 2)
          ((float*)outp)[(size_t)row * Nn + col] = resid[(size_t)row * Nn + col] + v;
        else
          ((short*)outp)[(size_t)row * Nn + col] = f2bf(v);
      }
    }
  }
}

// ---------------- flash attention: 128 q-rows/block, 64-key tiles ----------------
__global__ __launch_bounds__(256, 2)
void k_attn(const short* __restrict__ Q, const short* __restrict__ K,
            const short* __restrict__ Vt, short* __restrict__ O) {
  constexpr int LD = 72;   // 64 + 8 pad
  __shared__ short sQ[128 * LD];
  __shared__ short sK[64 * LD];
  __shared__ short sV[64 * LD];   // Vt tile: [d][key]
  __shared__ short sP[128 * LD];
  const int tid = threadIdx.x;
  const int bh = blockIdx.y;
  const int b = bh >> 4, h = bh & 15;
  const int q0 = blockIdx.x * 128;
  const int wave = tid >> 6, lane = tid & 63, quad = lane >> 4, l15 = lane & 15;
  const int wm = wave * 32;        // 32 q-rows per wave
  const size_t tokBase = (size_t)b * SEQ;

  #pragma unroll
  for (int i = 0; i < 4; i++) {
    int idx = tid + i * 256, row = idx >> 3, seg = idx & 7;
    *(int4*)&sQ[row * LD + seg * 8] =
        *(const int4*)(Q + (tokBase + q0 + row) * C + h * HD + seg * 8);
  }

  const f32x4 fzero = {0.f, 0.f, 0.f, 0.f};
  f32x4 o[2][4];
  float mrow[2][4], lrow[2][4];
  #pragma unroll
  for (int mi = 0; mi < 2; mi++) {
    #pragma unroll
    for (int di = 0; di < 4; di++) o[mi][di] = fzero;
    #pragma unroll
    for (int r = 0; r < 4; r++) { mrow[mi][r] = -1e30f; lrow[mi][r] = 0.f; }
  }

  for (int kb = 0; kb < SEQ / 64; kb++) {
    const int k0 = kb * 64;
    __syncthreads();   // previous PV reads of sK/sV complete
    #pragma unroll
    for (int i = 0; i < 2; i++) {
      int idx = tid + i * 256, row = idx >> 3, seg = idx & 7;
      *(int4*)&sK[row * LD + seg * 8] =
          *(const int4*)(K + (tokBase + k0 + row) * C + h * HD + seg * 8);
      *(int4*)&sV[row * LD + seg * 8] =
          *(const int4*)(Vt + ((size_t)bh * HD + row) * SEQ + k0 + seg * 8);
    }
    __syncthreads();

    // S = Q @ K^T  (A=Q rows, Bt=K rows; both contiguous in d)
    f32x4 s[2][4];
    #pragma unroll
    for (int mi = 0; mi < 2; mi++) {
      short8 a0 = *(const short8*)&sQ[(wm + mi * 16 + l15) * LD + quad * 8];
      short8 a1 = *(const short8*)&sQ[(wm + mi * 16 + l15) * LD + 32 + quad * 8];
      #pragma unroll
      for (int ni = 0; ni < 4; ni++) {
        short8 b0 = *(const short8*)&sK[(ni * 16 + l15) * LD + quad * 8];
        short8 b1 = *(const short8*)&sK[(ni * 16 + l15) * LD + 32 + quad * 8];
        f32x4 accv = __builtin_amdgcn_mfma_f32_16x16x32_bf16(a0, b0, fzero, 0, 0, 0);
        accv = __builtin_amdgcn_mfma_f32_16x16x32_bf16(a1, b1, accv, 0, 0, 0);
        s[mi][ni] = accv * 0.125f;   // scale = 64^-0.5
      }
    }

    // online softmax; row stats reduced across the quad's 16 lanes (cols)
    #pragma unroll
    for (int mi = 0; mi < 2; mi++) {
      #pragma unroll
      for (int r = 0; r < 4; r++) {
        float vmax = fmaxf(fmaxf(s[mi][0][r], s[mi][1][r]), fmaxf(s[mi][2][r], s[mi][3][r]));
        #pragma unroll
        for (int off = 8; off >= 1; off >>= 1) vmax = fmaxf(vmax, __shfl_xor(vmax, off, 16));
        float mn = fmaxf(mrow[mi][r], vmax);
        float alpha = __expf(mrow[mi][r] - mn);
        mrow[mi][r] = mn;
        float rs = 0.f;
        #pragma unroll
        for (int ni = 0; ni < 4; ni++) {
          float p = __expf(s[mi][ni][r] - mn);
          s[mi][ni][r] = p; rs += p;
        }
        #pragma unroll
        for (int off = 8; off >= 1; off >>= 1) rs += __shfl_xor(rs, off, 16);
        lrow[mi][r] = lrow[mi][r] * alpha + rs;
        #pragma unroll
        for (int di = 0; di < 4; di++) o[mi][di][r] *= alpha;
      }
      // C-layout -> A-layout via LDS round-trip
      #pragma unroll
      for (int ni = 0; ni < 4; ni++)
        #pragma unroll
        for (int r = 0; r < 4; r++)
          sP[(wm + mi * 16 + quad * 4 + r) * LD + ni * 16 + l15] = f2bf(s[mi][ni][r]);
    }
    __syncthreads();

    // O += P @ V  (A=P rows contiguous in key; Bt=sV[d][key] contiguous in key)
    #pragma unroll
    for (int mi = 0; mi < 2; mi++) {
      short8 a0 = *(const short8*)&sP[(wm + mi * 16 + l15) * LD + quad * 8];
      short8 a1 = *(const short8*)&sP[(wm + mi * 16 + l15) * LD + 32 + quad * 8];
      #pragma unroll
      for (int di = 0; di < 4; di++) {
        short8 b0 = *(const short8*)&sV[(di * 16 + l15) * LD + quad * 8];
        short8 b1 = *(const short8*)&sV[(di * 16 + l15) * LD + 32 + quad * 8];
        o[mi][di] = __builtin_amdgcn_mfma_f32_16x16x32_bf16(a0, b0, o[mi][di], 0, 0, 0);
        o[mi][di] = __builtin_amdgcn_mfma_f32_16x16x32_bf16(a1, b1, o[mi][di], 0, 0, 0);
      }
    }
  }

  #pragma unroll
  for (int mi = 0; mi < 2; mi++)
    #pragma unroll
    for (int di = 0; di < 4; di++)
      #pragma unroll
      for (int r = 0; r < 4; r++) {
        int row = q0 + wm + mi * 16 + quad * 4 + r;
        int col = h * HD + di * 16 + l15;
        O[(tokBase + row) * C + col] = f2bf(o[mi][di][r] / lrow[mi][r]);
      }
}

extern "C" void kernel_launch(void* const* d_in, const int* in_sizes, int n_in,
                              void* d_out, int out_size, void* d_ws, size_t ws_size,
                              hipStream_t stream) {
  // setup_inputs() dict order:
  const float* x   = (const float*)d_in[0];
  const float* pos = (const float*)d_in[1];
  const float* nqg = (const float*)d_in[2];
  const float* nqb = (const float*)d_in[3];
  const float* nkg = (const float*)d_in[4];
  const float* nkb = (const float*)d_in[5];
  const float* nvg = (const float*)d_in[6];
  const float* nvb = (const float*)d_in[7];
  const float* ng  = (const float*)d_in[8];
  const float* nb  = (const float*)d_in[9];
  const float* wq  = (const float*)d_in[10];
  const float* bq  = (const float*)d_in[11];
  const float* wk  = (const float*)d_in[12];
  const float* bk  = (const float*)d_in[13];
  const float* wv  = (const float*)d_in[14];
  const float* bv  = (const float*)d_in[15];
  const float* wp  = (const float*)d_in[16];
  const float* bp  = (const float*)d_in[17];
  const float* w1  = (const float*)d_in[18];
  const float* b1  = (const float*)d_in[19];
  const float* w2  = (const float*)d_in[20];
  const float* b2  = (const float*)d_in[21];

  char* ws = (char*)d_ws;
  const size_t MB = 1u << 20;
  short* wqT  = (short*)(ws + 0 * MB);     // 2 MB each (C*C bf16)
  short* wkT  = (short*)(ws + 2 * MB);
  short* wvT  = (short*)(ws + 4 * MB);
  short* wpT  = (short*)(ws + 6 * MB);
  short* w1T  = (short*)(ws + 8 * MB);     // 8 MB  [HID][C]
  short* w2T  = (short*)(ws + 16 * MB);    // 8 MB  [C][HID]
  short* xq   = (short*)(ws + 24 * MB);    // 16 MB each (MTOT*C bf16)
  short* xk   = (short*)(ws + 40 * MB);
  short* xv   = (short*)(ws + 56 * MB);
  short* Qm   = (short*)(ws + 72 * MB);
  short* Km   = (short*)(ws + 88 * MB);
  short* Vm   = (short*)(ws + 104 * MB);
  short* Vt   = (short*)(ws + 120 * MB);
  short* y1   = (short*)(ws + 72 * MB);    // 64 MB, overlays Q/K/V/Vt (dead after attn)
  short* Ob   = xk;                         // attn out overlays xk (dead after K-proj)
  short* hln  = xq;                         // overlays xq (dead after Q-proj)
  float* hbuf = (float*)(ws + 136 * MB);   // 32 MB fp32 residual h
  (void)ws_size; (void)in_sizes; (void)n_in; (void)out_size;

  dim3 blk(256);
  // weight prep (fp32 -> bf16, transposed to [N][K])
  k_transpose_w<<<dim3(32, 32),  blk, 0, stream>>>(wq, wqT, C, C);
  k_transpose_w<<<dim3(32, 32),  blk, 0, stream>>>(wk, wkT, C, C);
  k_transpose_w<<<dim3(32, 32),  blk, 0, stream>>>(wv, wvT, C, C);
  k_transpose_w<<<dim3(32, 32),  blk, 0, stream>>>(wp, wpT, C, C);
  k_transpose_w<<<dim3(128, 32), blk, 0, stream>>>(w1, w1T, C, HID);
  k_transpose_w<<<dim3(32, 128), blk, 0, stream>>>(w2, w2T, HID, C);
  // LayerNorms for q-input and kv-input
  k_ln_qkv<<<dim3(MTOT), blk, 0, stream>>>(x, pos, nqg, nqb, nkg, nkb, nvg, nvb, xq, xk, xv);
  // QKV projections
  k_gemm<0><<<dim3(C / 128, MTOT / 128), blk, 0, stream>>>(xq, wqT, bq, nullptr, Qm, C, C);
  k_gemm<0><<<dim3(C / 128, MTOT / 128), blk, 0, stream>>>(xk, wkT, bk, nullptr, Km, C, C);
  k_gemm<0><<<dim3(C / 128, MTOT / 128), blk, 0, stream>>>(xv, wvT, bv, nullptr, Vm, C, C);
  // V -> [b,h][d][n] for PV B-operand
  k_transpose_v<<<dim3(SEQ / 32, HD / 32, Bb * NH), blk, 0, stream>>>(Vm, Vt);
  // flash attention
  k_attn<<<dim3(SEQ / 128, Bb * NH), blk, 0, stream>>>(Qm, Km, Vt, Ob);
  // output projection + residual -> h (fp32)
  k_gemm<2><<<dim3(C / 128, MTOT / 128), blk, 0, stream>>>(Ob, wpT, bp, x, hbuf, C, C);
  // LN(h)
  k_ln1<<<dim3(MTOT), blk, 0, stream>>>(hbuf, ng, nb, hln);
  // MLP
  k_gemm<1><<<dim3(HID / 128, MTOT / 128), blk, 0, stream>>>(hln, w1T, b1, nullptr, y1, HID, C);
  k_gemm<2><<<dim3(C / 128, MTOT / 128), blk, 0, stream>>>(y1, w2T, b2, hbuf, (float*)d_out, C, HID);
}

// Round 3
// 627.682 us; speedup vs baseline: 1.2198x; 1.2198x over previous
//
#include <hip/hip_runtime.h>
#include <hip/hip_bf16.h>

#define DEV __device__ __forceinline__

typedef __attribute__((ext_vector_type(8))) short short8;
typedef __attribute__((ext_vector_type(4))) float f32x4;
typedef __attribute__((ext_vector_type(4))) int i32x4;

constexpr int Bb   = 4;
constexpr int SEQ  = 2048;
constexpr int C    = 1024;
constexpr int HID  = 4096;
constexpr int NH   = 16;
constexpr int HD   = 64;
constexpr int MTOT = Bb * SEQ;   // 8192 tokens

DEV unsigned bfbits(float f) {
  unsigned x = __float_as_uint(f);
  return (x + 0x7fffu + ((x >> 16) & 1u)) >> 16;   // RNE to bf16, low 16 bits
}

DEV short f2bf(float f) { return (short)bfbits(f); }

DEV unsigned packbf(float a, float b) {
  return bfbits(a) | (bfbits(b) << 16);   // a in low 16, b in high 16
}

DEV void gload16(const void* g, void* l) {
  __builtin_amdgcn_global_load_lds((const __attribute__((address_space(1))) void*)g,
                                   (__attribute__((address_space(3))) void*)l, 16, 0, 0);
}

// ---------------- weight transpose: fp32 [R][Cc] -> bf16 [Cc][R] ----------------
__global__ void k_transpose_w(const float* __restrict__ src, short* __restrict__ dst,
                              int R, int Cc) {
  __shared__ float t[32][33];
  int tx = threadIdx.x & 31, ty = threadIdx.x >> 5;   // 32 x 8
  int c0 = blockIdx.x * 32, r0 = blockIdx.y * 32;
  #pragma unroll
  for (int i = 0; i < 4; i++)
    t[ty + i * 8][tx] = src[(size_t)(r0 + ty + i * 8) * Cc + c0 + tx];
  __syncthreads();
  #pragma unroll
  for (int i = 0; i < 4; i++)
    dst[(size_t)(c0 + ty + i * 8) * R + r0 + tx] = f2bf(t[tx][ty + i * 8]);
}

// ---------------- V transpose: bf16 [tok][C] -> per-(b,h) [HD][SEQ] ----------------
__global__ void k_transpose_v(const short* __restrict__ V, short* __restrict__ Vt) {
  __shared__ short t[32][33];
  int tx = threadIdx.x & 31, ty = threadIdx.x >> 5;
  int plane = blockIdx.z;                 // b*16 + h
  int b = plane >> 4, h = plane & 15;
  int n0 = blockIdx.x * 32, d0 = blockIdx.y * 32;
  #pragma unroll
  for (int i = 0; i < 4; i++)
    t[ty + i * 8][tx] = V[(size_t)(b * SEQ + n0 + ty + i * 8) * C + h * HD + d0 + tx];
  __syncthreads();
  #pragma unroll
  for (int i = 0; i < 4; i++)
    Vt[((size_t)plane * HD + d0 + ty + i * 8) * SEQ + n0 + tx] = t[tx][ty + i * 8];
}

// ---------------- fused LN for q-input (x) and kv-input (x+pos) ----------------
__global__ void k_ln_qkv(const float* __restrict__ x, const float* __restrict__ pos,
                         const float* __restrict__ nqg, const float* __restrict__ nqb,
                         const float* __restrict__ nkg, const float* __restrict__ nkb,
                         const float* __restrict__ nvg, const float* __restrict__ nvb,
                         short* __restrict__ xq, short* __restrict__ xk,
                         short* __restrict__ xv) {
  int row = blockIdx.x, tid = threadIdx.x;
  int n = row & (SEQ - 1);
  float a4[4], p4[4];
  float s1 = 0, s2 = 0, t1 = 0, t2 = 0;
  #pragma unroll
  for (int i = 0; i < 4; i++) {
    int c = tid + i * 256;
    float a = x[(size_t)row * C + c];
    float p = pos[(size_t)n * C + c] + a;
    a4[i] = a; p4[i] = p;
    s1 += a; s2 += a * a; t1 += p; t2 += p * p;
  }
  #pragma unroll
  for (int off = 32; off; off >>= 1) {
    s1 += __shfl_xor(s1, off, 64);
    s2 += __shfl_xor(s2, off, 64);
    t1 += __shfl_xor(t1, off, 64);
    t2 += __shfl_xor(t2, off, 64);
  }
  __shared__ float red[4][4];
  int wave = tid >> 6, lane = tid & 63;
  if (lane == 0) { red[wave][0] = s1; red[wave][1] = s2; red[wave][2] = t1; red[wave][3] = t2; }
  __syncthreads();
  s1 = red[0][0] + red[1][0] + red[2][0] + red[3][0];
  s2 = red[0][1] + red[1][1] + red[2][1] + red[3][1];
  t1 = red[0][2] + red[1][2] + red[2][2] + red[3][2];
  t2 = red[0][3] + red[1][3] + red[2][3] + red[3][3];
  float mq = s1 * (1.f / C), mk = t1 * (1.f / C);
  float rq = rsqrtf(s2 * (1.f / C) - mq * mq + 1e-5f);
  float rk = rsqrtf(t2 * (1.f / C) - mk * mk + 1e-5f);
  #pragma unroll
  for (int i = 0; i < 4; i++) {
    int c = tid + i * 256;
    float nq_ = (a4[i] - mq) * rq;
    float nk_ = (p4[i] - mk) * rk;
    xq[(size_t)row * C + c] = f2bf(nq_ * nqg[c] + nqb[c]);
    xk[(size_t)row * C + c] = f2bf(nk_ * nkg[c] + nkb[c]);
    xv[(size_t)row * C + c] = f2bf(nk_ * nvg[c] + nvb[c]);
  }
}

// ---------------- plain LN (h -> bf16) ----------------
__global__ void k_ln1(const float* __restrict__ h, const float* __restrict__ g,
                      const float* __restrict__ bta, short* __restrict__ out) {
  int row = blockIdx.x, tid = threadIdx.x;
  float a4[4];
  float s1 = 0, s2 = 0;
  #pragma unroll
  for (int i = 0; i < 4; i++) {
    int c = tid + i * 256;
    float a = h[(size_t)row * C + c];
    a4[i] = a; s1 += a; s2 += a * a;
  }
  #pragma unroll
  for (int off = 32; off; off >>= 1) {
    s1 += __shfl_xor(s1, off, 64);
    s2 += __shfl_xor(s2, off, 64);
  }
  __shared__ float red[4][2];
  int wave = tid >> 6, lane = tid & 63;
  if (lane == 0) { red[wave][0] = s1; red[wave][1] = s2; }
  __syncthreads();
  s1 = red[0][0] + red[1][0] + red[2][0] + red[3][0];
  s2 = red[0][1] + red[1][1] + red[2][1] + red[3][1];
  float m = s1 * (1.f / C);
  float r = rsqrtf(s2 * (1.f / C) - m * m + 1e-5f);
  #pragma unroll
  for (int i = 0; i < 4; i++) {
    int c = tid + i * 256;
    out[(size_t)row * C + c] = f2bf((a4[i] - m) * r * g[c] + bta[c]);
  }
}

// ---------------- GEMM (m97 recipe): global_load_lds staging, unpadded LDS ----------------
// MODE 0: +bias -> bf16;  MODE 1: +bias, LeakyReLU(0.1) -> bf16;
// MODE 2: +bias+resid -> fp32;  MODE 3: (+bias)*0.125 -> bf16 (Q proj)
template <int MODE>
__global__ __launch_bounds__(256, 2)
void k_gemm(const short* __restrict__ A, const short* __restrict__ Bt,
            const float* __restrict__ bias, const float* __restrict__ resid,
            void* __restrict__ outp, int Nn, int Kk) {
  __shared__ short sA[128 * 32];
  __shared__ short sB[128 * 32];
  const int tid = threadIdx.x;
  const int n0 = blockIdx.x * 128, m0 = blockIdx.y * 128;
  const int wave = tid >> 6, lane = tid & 63, quad = lane >> 4, l15 = lane & 15;
  const int wm = (wave >> 1) * 64, wn = (wave & 1) * 64;

  // staging addresses: LDS side MUST be lane-contiguous (base + idx*16B) for global_load_lds
  const int r0 = tid >> 2, s0 = (tid & 3) * 8;
  const short* gA0 = A + (size_t)(m0 + r0) * Kk + s0;
  const short* gA1 = A + (size_t)(m0 + r0 + 64) * Kk + s0;
  const short* gB0 = Bt + (size_t)(n0 + r0) * Kk + s0;
  const short* gB1 = Bt + (size_t)(n0 + r0 + 64) * Kk + s0;
  short* lA0 = &sA[tid * 8];
  short* lA1 = &sA[(tid + 256) * 8];
  short* lB0 = &sB[tid * 8];
  short* lB1 = &sB[(tid + 256) * 8];

  const f32x4 fzero = {0.f, 0.f, 0.f, 0.f};
  f32x4 acc[4][4];
  #pragma unroll
  for (int mi = 0; mi < 4; mi++)
    #pragma unroll
    for (int ni = 0; ni < 4; ni++) acc[mi][ni] = fzero;

  for (int k0 = 0; k0 < Kk; k0 += 32) {
    gload16(gA0 + k0, lA0);
    gload16(gA1 + k0, lA1);
    gload16(gB0 + k0, lB0);
    gload16(gB1 + k0, lB1);
    __syncthreads();   // drains vmcnt (global_load_lds) per barrier semantics
    short8 av[4], bv[4];
    #pragma unroll
    for (int mi = 0; mi < 4; mi++)
      av[mi] = *(const short8*)&sA[(wm + mi * 16 + l15) * 32 + quad * 8];
    #pragma unroll
    for (int ni = 0; ni < 4; ni++)
      bv[ni] = *(const short8*)&sB[(wn + ni * 16 + l15) * 32 + quad * 8];
    #pragma unroll
    for (int mi = 0; mi < 4; mi++)
      #pragma unroll
      for (int ni = 0; ni < 4; ni++)
        acc[mi][ni] = __builtin_amdgcn_mfma_f32_16x16x32_bf16(av[mi], bv[ni], acc[mi][ni], 0, 0, 0);
    __syncthreads();
  }

  float bb[4];
  #pragma unroll
  for (int ni = 0; ni < 4; ni++) bb[ni] = bias[n0 + wn + ni * 16 + l15];

  #pragma unroll
  for (int mi = 0; mi < 4; mi++) {
    #pragma unroll
    for (int ni = 0; ni < 4; ni++) {
      #pragma unroll
      for (int r = 0; r < 4; r++) {
        int row = m0 + wm + mi * 16 + quad * 4 + r;   // C/D layout: row=quad*4+reg
        int col = n0 + wn + ni * 16 + l15;            //             col=lane&15
        float v = acc[mi][ni][r] + bb[ni];
        if constexpr (MODE == 1) v = v >= 0.f ? v : 0.1f * v;
        if constexpr (MODE == 3) v *= 0.125f;         // attn scale folded into Q
        if constexpr (MODE == 2)
          ((float*)outp)[(size_t)row * Nn + col] = resid[(size_t)row * Nn + col] + v;
        else
          ((short*)outp)[(size_t)row * Nn + col] = f2bf(v);
      }
    }
  }
}

// ---------------- flash attention, S^T formulation ----------------
// No online max (scores bounded: |s| ~ 2 << 85): unnormalized exp + final divide.
// S^T = K @ Q^T puts q on lane&15 -> row-sum is VALU + 2 quad-shuffles; P moves to
// PV A-fragment layout with register shuffles (no sP LDS, no 3rd barrier).
__global__ __launch_bounds__(256, 4)
void k_attn(const short* __restrict__ Q, const short* __restrict__ K,
            const short* __restrict__ Vt, short* __restrict__ O) {
  constexpr int LD = 72;   // 64 + 8 pad
  __shared__ short sQ[128 * LD];
  __shared__ short sK[64 * LD];
  __shared__ short sV[64 * LD];   // Vt tile: [d][key]
  const int tid = threadIdx.x;
  const int bh = blockIdx.y;
  const int b = bh >> 4, h = bh & 15;
  const int q0 = blockIdx.x * 128;
  const int wave = tid >> 6, lane = tid & 63, quad = lane >> 4, l15 = lane & 15;
  const int wm = wave * 32;        // 32 q-rows per wave
  const size_t tokBase = (size_t)b * SEQ;

  #pragma unroll
  for (int i = 0; i < 4; i++) {
    int idx = tid + i * 256, row = idx >> 3, seg = idx & 7;
    *(int4*)&sQ[row * LD + seg * 8] =
        *(const int4*)(Q + (tokBase + q0 + row) * C + h * HD + seg * 8);
  }

  const f32x4 fzero = {0.f, 0.f, 0.f, 0.f};
  f32x4 o[2][4];
  float lsum[2] = {0.f, 0.f};
  #pragma unroll
  for (int qi = 0; qi < 2; qi++)
    #pragma unroll
    for (int di = 0; di < 4; di++) o[qi][di] = fzero;

  const int selHi = quad >> 1;               // quads 2,3 take the odd 16-key tile
  const int srcL0 = ((quad & 1) * 2) * 16 + l15;       // source lane, frag ints 0,1
  const int srcL1 = ((quad & 1) * 2 + 1) * 16 + l15;   // source lane, frag ints 2,3

  for (int kb = 0; kb < SEQ / 64; kb++) {
    const int k0 = kb * 64;
    __syncthreads();   // previous iteration's reads of sK/sV complete
    #pragma unroll
    for (int i = 0; i < 2; i++) {
      int idx = tid + i * 256, row = idx >> 3, seg = idx & 7;
      *(int4*)&sK[row * LD + seg * 8] =
          *(const int4*)(K + (tokBase + k0 + row) * C + h * HD + seg * 8);
      *(int4*)&sV[row * LD + seg * 8] =
          *(const int4*)(Vt + ((size_t)bh * HD + row) * SEQ + k0 + seg * 8);
    }
    __syncthreads();

    // S^T tiles: D[key][q], key=quad*4+r, q=l15.  exp + pack immediately (keeps VGPRs low).
    unsigned pk[4][2][2];
    float csum[2] = {0.f, 0.f};
    #pragma unroll
    for (int qi = 0; qi < 2; qi++) {
      short8 b0 = *(const short8*)&sQ[(wm + qi * 16 + l15) * LD + quad * 8];
      short8 b1 = *(const short8*)&sQ[(wm + qi * 16 + l15) * LD + 32 + quad * 8];
      #pragma unroll
      for (int ki = 0; ki < 4; ki++) {
        short8 a0 = *(const short8*)&sK[(ki * 16 + l15) * LD + quad * 8];
        short8 a1 = *(const short8*)&sK[(ki * 16 + l15) * LD + 32 + quad * 8];
        f32x4 st = __builtin_amdgcn_mfma_f32_16x16x32_bf16(a0, b0, fzero, 0, 0, 0);
        st = __builtin_amdgcn_mfma_f32_16x16x32_bf16(a1, b1, st, 0, 0, 0);
        float p0 = __expf(st[0]), p1 = __expf(st[1]);
        float p2 = __expf(st[2]), p3 = __expf(st[3]);
        csum[qi] += (p0 + p1) + (p2 + p3);
        pk[ki][qi][0] = packbf(p0, p1);
        pk[ki][qi][1] = packbf(p2, p3);
      }
    }
    #pragma unroll
    for (int qi = 0; qi < 2; qi++) {
      float v = csum[qi];
      v += __shfl_xor(v, 16, 64);
      v += __shfl_xor(v, 32, 64);
      lsum[qi] += v;     // total over this 64-key tile, for q = l15
    }

    // P -> A-fragment via register shuffles, then PV
    #pragma unroll
    for (int kc = 0; kc < 2; kc++) {
      #pragma unroll
      for (int qi = 0; qi < 2; qi++) {
        i32x4 fr;
        int vA, vB;
        vA = __shfl((int)pk[2 * kc][qi][0], srcL0, 64);
        vB = __shfl((int)pk[2 * kc + 1][qi][0], srcL0, 64);
        fr.x = selHi ? vB : vA;
        vA = __shfl((int)pk[2 * kc][qi][1], srcL0, 64);
        vB = __shfl((int)pk[2 * kc + 1][qi][1], srcL0, 64);
        fr.y = selHi ? vB : vA;
        vA = __shfl((int)pk[2 * kc][qi][0], srcL1, 64);
        vB = __shfl((int)pk[2 * kc + 1][qi][0], srcL1, 64);
        fr.z = selHi ? vB : vA;
        vA = __shfl((int)pk[2 * kc][qi][1], srcL1, 64);
        vB = __shfl((int)pk[2 * kc + 1][qi][1], srcL1, 64);
        fr.w = selHi ? vB : vA;
        short8 aP = __builtin_bit_cast(short8, fr);
        #pragma unroll
        for (int di = 0; di < 4; di++) {
          short8 bv = *(const short8*)&sV[(di * 16 + l15) * LD + kc * 32 + quad * 8];
          o[qi][di] = __builtin_amdgcn_mfma_f32_16x16x32_bf16(aP, bv, o[qi][di], 0, 0, 0);
        }
      }
    }
  }

  // final normalize: sum for q=quad*4+r lives at lane l15=q (any quad)
  float linv[2][4];
  #pragma unroll
  for (int qi = 0; qi < 2; qi++)
    #pragma unroll
    for (int r = 0; r < 4; r++)
      linv[qi][r] = 1.0f / __shfl(lsum[qi], quad * 4 + r, 64);

  #pragma unroll
  for (int qi = 0; qi < 2; qi++)
    #pragma unroll
    for (int di = 0; di < 4; di++)
      #pragma unroll
      for (int r = 0; r < 4; r++) {
        int row = q0 + wm + qi * 16 + quad * 4 + r;
        int col = h * HD + di * 16 + l15;
        O[(tokBase + row) * C + col] = f2bf(o[qi][di][r] * linv[qi][r]);
      }
}

extern "C" void kernel_launch(void* const* d_in, const int* in_sizes, int n_in,
                              void* d_out, int out_size, void* d_ws, size_t ws_size,
                              hipStream_t stream) {
  const float* x   = (const float*)d_in[0];
  const float* pos = (const float*)d_in[1];
  const float* nqg = (const float*)d_in[2];
  const float* nqb = (const float*)d_in[3];
  const float* nkg = (const float*)d_in[4];
  const float* nkb = (const float*)d_in[5];
  const float* nvg = (const float*)d_in[6];
  const float* nvb = (const float*)d_in[7];
  const float* ng  = (const float*)d_in[8];
  const float* nb  = (const float*)d_in[9];
  const float* wq  = (const float*)d_in[10];
  const float* bq  = (const float*)d_in[11];
  const float* wk  = (const float*)d_in[12];
  const float* bk  = (const float*)d_in[13];
  const float* wv  = (const float*)d_in[14];
  const float* bv  = (const float*)d_in[15];
  const float* wp  = (const float*)d_in[16];
  const float* bp  = (const float*)d_in[17];
  const float* w1  = (const float*)d_in[18];
  const float* b1  = (const float*)d_in[19];
  const float* w2  = (const float*)d_in[20];
  const float* b2  = (const float*)d_in[21];

  char* ws = (char*)d_ws;
  const size_t MB = 1u << 20;
  short* wqT  = (short*)(ws + 0 * MB);
  short* wkT  = (short*)(ws + 2 * MB);
  short* wvT  = (short*)(ws + 4 * MB);
  short* wpT  = (short*)(ws + 6 * MB);
  short* w1T  = (short*)(ws + 8 * MB);     // [HID][C]
  short* w2T  = (short*)(ws + 16 * MB);    // [C][HID]
  short* xq   = (short*)(ws + 24 * MB);
  short* xk   = (short*)(ws + 40 * MB);
  short* xv   = (short*)(ws + 56 * MB);
  short* Qm   = (short*)(ws + 72 * MB);
  short* Km   = (short*)(ws + 88 * MB);
  short* Vm   = (short*)(ws + 104 * MB);
  short* Vt   = (short*)(ws + 120 * MB);
  short* y1   = (short*)(ws + 72 * MB);    // overlays Q/K/V/Vt (dead after attn)
  short* Ob   = xk;                         // overlays xk (dead after K-proj)
  short* hln  = xq;                         // overlays xq (dead after Q-proj)
  float* hbuf = (float*)(ws + 136 * MB);
  (void)ws_size; (void)in_sizes; (void)n_in; (void)out_size;

  dim3 blk(256);
  k_transpose_w<<<dim3(32, 32),  blk, 0, stream>>>(wq, wqT, C, C);
  k_transpose_w<<<dim3(32, 32),  blk, 0, stream>>>(wk, wkT, C, C);
  k_transpose_w<<<dim3(32, 32),  blk, 0, stream>>>(wv, wvT, C, C);
  k_transpose_w<<<dim3(32, 32),  blk, 0, stream>>>(wp, wpT, C, C);
  k_transpose_w<<<dim3(128, 32), blk, 0, stream>>>(w1, w1T, C, HID);
  k_transpose_w<<<dim3(32, 128), blk, 0, stream>>>(w2, w2T, HID, C);
  k_ln_qkv<<<dim3(MTOT), blk, 0, stream>>>(x, pos, nqg, nqb, nkg, nkb, nvg, nvb, xq, xk, xv);
  k_gemm<3><<<dim3(C / 128, MTOT / 128), blk, 0, stream>>>(xq, wqT, bq, nullptr, Qm, C, C);
  k_gemm<0><<<dim3(C / 128, MTOT / 128), blk, 0, stream>>>(xk, wkT, bk, nullptr, Km, C, C);
  k_gemm<0><<<dim3(C / 128, MTOT / 128), blk, 0, stream>>>(xv, wvT, bv, nullptr, Vm, C, C);
  k_transpose_v<<<dim3(SEQ / 32, HD / 32, Bb * NH), blk, 0, stream>>>(Vm, Vt);
  k_attn<<<dim3(SEQ / 128, Bb * NH), blk, 0, stream>>>(Qm, Km, Vt, Ob);
  k_gemm<2><<<dim3(C / 128, MTOT / 128), blk, 0, stream>>>(Ob, wpT, bp, x, hbuf, C, C);
  k_ln1<<<dim3(MTOT), blk, 0, stream>>>(hbuf, ng, nb, hln);
  k_gemm<1><<<dim3(HID / 128, MTOT / 128), blk, 0, stream>>>(hln, w1T, b1, nullptr, y1, HID, C);
  k_gemm<2><<<dim3(C / 128, MTOT / 128), blk, 0, stream>>>(y1, w2T, b2, hbuf, (float*)d_out, C, HID);
}

// Round 4
// 619.204 us; speedup vs baseline: 1.2366x; 1.0137x over previous
//
#include <hip/hip_runtime.h>
#include <hip/hip_bf16.h>

#define DEV __device__ __forceinline__

typedef __attribute__((ext_vector_type(8))) short short8;
typedef __attribute__((ext_vector_type(4))) float f32x4;
typedef __attribute__((ext_vector_type(4))) int i32x4;

constexpr int Bb   = 4;
constexpr int SEQ  = 2048;
constexpr int C    = 1024;
constexpr int HID  = 4096;
constexpr int NH   = 16;
constexpr int HD   = 64;
constexpr int MTOT = Bb * SEQ;   // 8192 tokens

DEV unsigned bfbits(float f) {
  unsigned x = __float_as_uint(f);
  return (x + 0x7fffu + ((x >> 16) & 1u)) >> 16;   // RNE to bf16, low 16 bits
}

DEV short f2bf(float f) { return (short)bfbits(f); }

// fast bf16 pair pack: +0x8000 (round-half-up, inputs always positive finite) + byte perm
DEV unsigned packrn(float a, float b) {
  unsigned ua = __float_as_uint(a) + 0x8000u;
  unsigned ub = __float_as_uint(b) + 0x8000u;
  // pool: bytes0-3 = ua, bytes4-7 = ub; take ua[2,3] -> low, ub[2,3] -> high
  return __builtin_amdgcn_perm(ub, ua, 0x07060302u);
}

DEV void gload16(const void* g, void* l) {
  __builtin_amdgcn_global_load_lds((const __attribute__((address_space(1))) void*)g,
                                   (__attribute__((address_space(3))) void*)l, 16, 0, 0);
}

// ---------------- weight transpose: fp32 [R][Cc] -> bf16 [Cc][R] ----------------
__global__ void k_transpose_w(const float* __restrict__ src, short* __restrict__ dst,
                              int R, int Cc) {
  __shared__ float t[32][33];
  int tx = threadIdx.x & 31, ty = threadIdx.x >> 5;   // 32 x 8
  int c0 = blockIdx.x * 32, r0 = blockIdx.y * 32;
  #pragma unroll
  for (int i = 0; i < 4; i++)
    t[ty + i * 8][tx] = src[(size_t)(r0 + ty + i * 8) * Cc + c0 + tx];
  __syncthreads();
  #pragma unroll
  for (int i = 0; i < 4; i++)
    dst[(size_t)(c0 + ty + i * 8) * R + r0 + tx] = f2bf(t[tx][ty + i * 8]);
}

// ---------------- V transpose: bf16 [tok][C] -> per-(b,h) [HD][SEQ] ----------------
__global__ void k_transpose_v(const short* __restrict__ V, short* __restrict__ Vt) {
  __shared__ short t[32][33];
  int tx = threadIdx.x & 31, ty = threadIdx.x >> 5;
  int plane = blockIdx.z;                 // b*16 + h
  int b = plane >> 4, h = plane & 15;
  int n0 = blockIdx.x * 32, d0 = blockIdx.y * 32;
  #pragma unroll
  for (int i = 0; i < 4; i++)
    t[ty + i * 8][tx] = V[(size_t)(b * SEQ + n0 + ty + i * 8) * C + h * HD + d0 + tx];
  __syncthreads();
  #pragma unroll
  for (int i = 0; i < 4; i++)
    Vt[((size_t)plane * HD + d0 + ty + i * 8) * SEQ + n0 + tx] = t[tx][ty + i * 8];
}

// ---------------- fused LN for q-input (x) and kv-input (x+pos) ----------------
__global__ void k_ln_qkv(const float* __restrict__ x, const float* __restrict__ pos,
                         const float* __restrict__ nqg, const float* __restrict__ nqb,
                         const float* __restrict__ nkg, const float* __restrict__ nkb,
                         const float* __restrict__ nvg, const float* __restrict__ nvb,
                         short* __restrict__ xq, short* __restrict__ xk,
                         short* __restrict__ xv) {
  int row = blockIdx.x, tid = threadIdx.x;
  int n = row & (SEQ - 1);
  float a4[4], p4[4];
  float s1 = 0, s2 = 0, t1 = 0, t2 = 0;
  #pragma unroll
  for (int i = 0; i < 4; i++) {
    int c = tid + i * 256;
    float a = x[(size_t)row * C + c];
    float p = pos[(size_t)n * C + c] + a;
    a4[i] = a; p4[i] = p;
    s1 += a; s2 += a * a; t1 += p; t2 += p * p;
  }
  #pragma unroll
  for (int off = 32; off; off >>= 1) {
    s1 += __shfl_xor(s1, off, 64);
    s2 += __shfl_xor(s2, off, 64);
    t1 += __shfl_xor(t1, off, 64);
    t2 += __shfl_xor(t2, off, 64);
  }
  __shared__ float red[4][4];
  int wave = tid >> 6, lane = tid & 63;
  if (lane == 0) { red[wave][0] = s1; red[wave][1] = s2; red[wave][2] = t1; red[wave][3] = t2; }
  __syncthreads();
  s1 = red[0][0] + red[1][0] + red[2][0] + red[3][0];
  s2 = red[0][1] + red[1][1] + red[2][1] + red[3][1];
  t1 = red[0][2] + red[1][2] + red[2][2] + red[3][2];
  t2 = red[0][3] + red[1][3] + red[2][3] + red[3][3];
  float mq = s1 * (1.f / C), mk = t1 * (1.f / C);
  float rq = rsqrtf(s2 * (1.f / C) - mq * mq + 1e-5f);
  float rk = rsqrtf(t2 * (1.f / C) - mk * mk + 1e-5f);
  #pragma unroll
  for (int i = 0; i < 4; i++) {
    int c = tid + i * 256;
    float nq_ = (a4[i] - mq) * rq;
    float nk_ = (p4[i] - mk) * rk;
    xq[(size_t)row * C + c] = f2bf(nq_ * nqg[c] + nqb[c]);
    xk[(size_t)row * C + c] = f2bf(nk_ * nkg[c] + nkb[c]);
    xv[(size_t)row * C + c] = f2bf(nk_ * nvg[c] + nvb[c]);
  }
}

// ---------------- plain LN (h -> bf16) ----------------
__global__ void k_ln1(const float* __restrict__ h, const float* __restrict__ g,
                      const float* __restrict__ bta, short* __restrict__ out) {
  int row = blockIdx.x, tid = threadIdx.x;
  float a4[4];
  float s1 = 0, s2 = 0;
  #pragma unroll
  for (int i = 0; i < 4; i++) {
    int c = tid + i * 256;
    float a = h[(size_t)row * C + c];
    a4[i] = a; s1 += a; s2 += a * a;
  }
  #pragma unroll
  for (int off = 32; off; off >>= 1) {
    s1 += __shfl_xor(s1, off, 64);
    s2 += __shfl_xor(s2, off, 64);
  }
  __shared__ float red[4][2];
  int wave = tid >> 6, lane = tid & 63;
  if (lane == 0) { red[wave][0] = s1; red[wave][1] = s2; }
  __syncthreads();
  s1 = red[0][0] + red[1][0] + red[2][0] + red[3][0];
  s2 = red[0][1] + red[1][1] + red[2][1] + red[3][1];
  float m = s1 * (1.f / C);
  float r = rsqrtf(s2 * (1.f / C) - m * m + 1e-5f);
  #pragma unroll
  for (int i = 0; i < 4; i++) {
    int c = tid + i * 256;
    out[(size_t)row * C + c] = f2bf((a4[i] - m) * r * g[c] + bta[c]);
  }
}

// ---------------- GEMM (m97 recipe): global_load_lds staging, unpadded LDS ----------------
// MODE 0: +bias -> bf16;  MODE 1: +bias, LeakyReLU(0.1) -> bf16;
// MODE 2: +bias+resid -> fp32;  MODE 3: (+bias)*0.125*log2e -> bf16 (Q proj, exp2-folded)
template <int MODE>
__global__ __launch_bounds__(256, 2)
void k_gemm(const short* __restrict__ A, const short* __restrict__ Bt,
            const float* __restrict__ bias, const float* __restrict__ resid,
            void* __restrict__ outp, int Nn, int Kk) {
  __shared__ short sA[128 * 32];
  __shared__ short sB[128 * 32];
  const int tid = threadIdx.x;
  const int n0 = blockIdx.x * 128, m0 = blockIdx.y * 128;
  const int wave = tid >> 6, lane = tid & 63, quad = lane >> 4, l15 = lane & 15;
  const int wm = (wave >> 1) * 64, wn = (wave & 1) * 64;

  const int r0 = tid >> 2, s0 = (tid & 3) * 8;
  const short* gA0 = A + (size_t)(m0 + r0) * Kk + s0;
  const short* gA1 = A + (size_t)(m0 + r0 + 64) * Kk + s0;
  const short* gB0 = Bt + (size_t)(n0 + r0) * Kk + s0;
  const short* gB1 = Bt + (size_t)(n0 + r0 + 64) * Kk + s0;
  short* lA0 = &sA[tid * 8];
  short* lA1 = &sA[(tid + 256) * 8];
  short* lB0 = &sB[tid * 8];
  short* lB1 = &sB[(tid + 256) * 8];

  const f32x4 fzero = {0.f, 0.f, 0.f, 0.f};
  f32x4 acc[4][4];
  #pragma unroll
  for (int mi = 0; mi < 4; mi++)
    #pragma unroll
    for (int ni = 0; ni < 4; ni++) acc[mi][ni] = fzero;

  for (int k0 = 0; k0 < Kk; k0 += 32) {
    gload16(gA0 + k0, lA0);
    gload16(gA1 + k0, lA1);
    gload16(gB0 + k0, lB0);
    gload16(gB1 + k0, lB1);
    __syncthreads();
    short8 av[4], bv[4];
    #pragma unroll
    for (int mi = 0; mi < 4; mi++)
      av[mi] = *(const short8*)&sA[(wm + mi * 16 + l15) * 32 + quad * 8];
    #pragma unroll
    for (int ni = 0; ni < 4; ni++)
      bv[ni] = *(const short8*)&sB[(wn + ni * 16 + l15) * 32 + quad * 8];
    #pragma unroll
    for (int mi = 0; mi < 4; mi++)
      #pragma unroll
      for (int ni = 0; ni < 4; ni++)
        acc[mi][ni] = __builtin_amdgcn_mfma_f32_16x16x32_bf16(av[mi], bv[ni], acc[mi][ni], 0, 0, 0);
    __syncthreads();
  }

  float bb[4];
  #pragma unroll
  for (int ni = 0; ni < 4; ni++) bb[ni] = bias[n0 + wn + ni * 16 + l15];

  #pragma unroll
  for (int mi = 0; mi < 4; mi++) {
    #pragma unroll
    for (int ni = 0; ni < 4; ni++) {
      #pragma unroll
      for (int r = 0; r < 4; r++) {
        int row = m0 + wm + mi * 16 + quad * 4 + r;   // C/D layout: row=quad*4+reg
        int col = n0 + wn + ni * 16 + l15;            //             col=lane&15
        float v = acc[mi][ni][r] + bb[ni];
        if constexpr (MODE == 1) v = v >= 0.f ? v : 0.1f * v;
        if constexpr (MODE == 3) v *= 0.1803368801111244f;   // 0.125 * log2(e)
        if constexpr (MODE == 2)
          ((float*)outp)[(size_t)row * Nn + col] = resid[(size_t)row * Nn + col] + v;
        else
          ((short*)outp)[(size_t)row * Nn + col] = f2bf(v);
      }
    }
  }
}

// ---------------- flash attention, S^T formulation, async double-buffered K/V ----------------
// Q fragments live in registers; sK/sV double-buffered via global_load_lds with a single
// barrier per 64-key tile (prefetch in flight during compute). Unnormalized exp2 + final
// divide (scores bounded; log2e folded into Q-proj). XOR seg-swizzle breaks bank aliasing.
__global__ __launch_bounds__(256, 4)
void k_attn(const short* __restrict__ Q, const short* __restrict__ K,
            const short* __restrict__ Vt, short* __restrict__ O) {
  __shared__ __align__(16) short sK[2][64 * 64];
  __shared__ __align__(16) short sV[2][64 * 64];   // Vt tile: [d][key]
  const int tid = threadIdx.x;
  const int bh = blockIdx.x;                        // bh fastest -> XCD-pinned K/V reuse
  const int b = bh >> 4, h = bh & 15;
  const int q0 = blockIdx.y * 128;
  const int wave = tid >> 6, lane = tid & 63, quad = lane >> 4, l15 = lane & 15;
  const int wm = wave * 32;        // 32 q-rows per wave
  const size_t tokBase = (size_t)b * SEQ;

  // Q fragments in registers (B-operand): [qi][d-half]
  short8 qf[2][2];
  #pragma unroll
  for (int qi = 0; qi < 2; qi++)
    #pragma unroll
    for (int hf = 0; hf < 2; hf++)
      qf[qi][hf] = *(const short8*)(Q + (tokBase + q0 + wm + qi * 16 + l15) * C
                                    + h * HD + hf * 32 + quad * 8);

  // staging: 2 slots/thread/array; store global seg (slot&7)^(row&7) at phys seg slot&7
  const int r0 = tid >> 3,        c0s = ((tid & 7) ^ (r0 & 7)) * 8;
  const int r1 = (tid + 256) >> 3, c1s = ((tid & 7) ^ (r1 & 7)) * 8;
  const short* gK0 = K + (tokBase + r0) * C + h * HD + c0s;
  const short* gK1 = K + (tokBase + r1) * C + h * HD + c1s;
  const short* gV0 = Vt + ((size_t)bh * HD + r0) * SEQ + c0s;
  const short* gV1 = Vt + ((size_t)bh * HD + r1) * SEQ + c1s;
  short* lK0 = &sK[0][tid * 8];
  short* lK1 = &sK[0][(tid + 256) * 8];
  short* lV0 = &sV[0][tid * 8];
  short* lV1 = &sV[0][(tid + 256) * 8];
  constexpr int BUFO = 64 * 64;   // shorts per buffer

#define STAGE(bufsel, kb) {                                   \
    int kk = (kb) * 64, bo = (bufsel) * BUFO;                 \
    gload16(gK0 + (size_t)kk * C, lK0 + bo);                  \
    gload16(gK1 + (size_t)kk * C, lK1 + bo);                  \
    gload16(gV0 + kk,             lV0 + bo);                  \
    gload16(gV1 + kk,             lV1 + bo); }

  const f32x4 fzero = {0.f, 0.f, 0.f, 0.f};
  f32x4 o[2][4];
  float lsum[2] = {0.f, 0.f};
  #pragma unroll
  for (int qi = 0; qi < 2; qi++)
    #pragma unroll
    for (int di = 0; di < 4; di++) o[qi][di] = fzero;

  const int selHi = quad >> 1;               // quads 2,3 take the odd 16-key tile
  const int srcL0 = ((quad & 1) * 2) * 16 + l15;       // source lane, frag ints 0,1
  const int srcL1 = ((quad & 1) * 2 + 1) * 16 + l15;   // source lane, frag ints 2,3
  const int sw = l15 & 7;                    // seg swizzle key

  STAGE(0, 0)

  for (int kb = 0; kb < SEQ / 64; kb++) {
    const int buf = kb & 1;
    __syncthreads();                         // drains prefetch vmcnt; guards buf reuse
    if (kb + 1 < SEQ / 64) STAGE(buf ^ 1, kb + 1)

    // S^T tiles: D[key][q], key=quad*4+r (within ki*16), q=l15; exp2 + pack immediately
    unsigned pk[4][2][2];
    float csum[2] = {0.f, 0.f};
    #pragma unroll
    for (int ki = 0; ki < 4; ki++) {
      const int krow = (ki * 16 + l15) * 64;
      short8 a0 = *(const short8*)&sK[buf][krow + ((0 + quad) ^ sw) * 8];
      short8 a1 = *(const short8*)&sK[buf][krow + ((4 + quad) ^ sw) * 8];
      #pragma unroll
      for (int qi = 0; qi < 2; qi++) {
        f32x4 st = __builtin_amdgcn_mfma_f32_16x16x32_bf16(a0, qf[qi][0], fzero, 0, 0, 0);
        st = __builtin_amdgcn_mfma_f32_16x16x32_bf16(a1, qf[qi][1], st, 0, 0, 0);
        float p0 = exp2f(st[0]), p1 = exp2f(st[1]);
        float p2 = exp2f(st[2]), p3 = exp2f(st[3]);
        csum[qi] += (p0 + p1) + (p2 + p3);
        pk[ki][qi][0] = packrn(p0, p1);
        pk[ki][qi][1] = packrn(p2, p3);
      }
    }
    #pragma unroll
    for (int qi = 0; qi < 2; qi++) {
      float v = csum[qi];
      v += __shfl_xor(v, 16, 64);
      v += __shfl_xor(v, 32, 64);
      lsum[qi] += v;     // 64-key-tile total for q = l15
    }

    // P -> A-fragment via register shuffles, then PV
    #pragma unroll
    for (int kc = 0; kc < 2; kc++) {
      short8 bv[4];
      #pragma unroll
      for (int di = 0; di < 4; di++)
        bv[di] = *(const short8*)&sV[buf][(di * 16 + l15) * 64 + ((kc * 4 + quad) ^ sw) * 8];
      #pragma unroll
      for (int qi = 0; qi < 2; qi++) {
        i32x4 fr;
        int vA, vB;
        vA = __shfl((int)pk[2 * kc][qi][0], srcL0, 64);
        vB = __shfl((int)pk[2 * kc + 1][qi][0], srcL0, 64);
        fr.x = selHi ? vB : vA;
        vA = __shfl((int)pk[2 * kc][qi][1], srcL0, 64);
        vB = __shfl((int)pk[2 * kc + 1][qi][1], srcL0, 64);
        fr.y = selHi ? vB : vA;
        vA = __shfl((int)pk[2 * kc][qi][0], srcL1, 64);
        vB = __shfl((int)pk[2 * kc + 1][qi][0], srcL1, 64);
        fr.z = selHi ? vB : vA;
        vA = __shfl((int)pk[2 * kc][qi][1], srcL1, 64);
        vB = __shfl((int)pk[2 * kc + 1][qi][1], srcL1, 64);
        fr.w = selHi ? vB : vA;
        short8 aP = __builtin_bit_cast(short8, fr);
        #pragma unroll
        for (int di = 0; di < 4; di++)
          o[qi][di] = __builtin_amdgcn_mfma_f32_16x16x32_bf16(aP, bv[di], o[qi][di], 0, 0, 0);
      }
    }
  }
#undef STAGE

  // final normalize: sum for q=quad*4+r lives at lane l15=q (any quad)
  float linv[2][4];
  #pragma unroll
  for (int qi = 0; qi < 2; qi++)
    #pragma unroll
    for (int r = 0; r < 4; r++)
      linv[qi][r] = 1.0f / __shfl(lsum[qi], quad * 4 + r, 64);

  #pragma unroll
  for (int qi = 0; qi < 2; qi++)
    #pragma unroll
    for (int di = 0; di < 4; di++)
      #pragma unroll
      for (int r = 0; r < 4; r++) {
        int row = q0 + wm + qi * 16 + quad * 4 + r;
        int col = h * HD + di * 16 + l15;
        O[(tokBase + row) * C + col] = f2bf(o[qi][di][r] * linv[qi][r]);
      }
}

extern "C" void kernel_launch(void* const* d_in, const int* in_sizes, int n_in,
                              void* d_out, int out_size, void* d_ws, size_t ws_size,
                              hipStream_t stream) {
  const float* x   = (const float*)d_in[0];
  const float* pos = (const float*)d_in[1];
  const float* nqg = (const float*)d_in[2];
  const float* nqb = (const float*)d_in[3];
  const float* nkg = (const float*)d_in[4];
  const float* nkb = (const float*)d_in[5];
  const float* nvg = (const float*)d_in[6];
  const float* nvb = (const float*)d_in[7];
  const float* ng  = (const float*)d_in[8];
  const float* nb  = (const float*)d_in[9];
  const float* wq  = (const float*)d_in[10];
  const float* bq  = (const float*)d_in[11];
  const float* wk  = (const float*)d_in[12];
  const float* bk  = (const float*)d_in[13];
  const float* wv  = (const float*)d_in[14];
  const float* bv  = (const float*)d_in[15];
  const float* wp  = (const float*)d_in[16];
  const float* bp  = (const float*)d_in[17];
  const float* w1  = (const float*)d_in[18];
  const float* b1  = (const float*)d_in[19];
  const float* w2  = (const float*)d_in[20];
  const float* b2  = (const float*)d_in[21];

  char* ws = (char*)d_ws;
  const size_t MB = 1u << 20;
  short* wqT  = (short*)(ws + 0 * MB);
  short* wkT  = (short*)(ws + 2 * MB);
  short* wvT  = (short*)(ws + 4 * MB);
  short* wpT  = (short*)(ws + 6 * MB);
  short* w1T  = (short*)(ws + 8 * MB);     // [HID][C]
  short* w2T  = (short*)(ws + 16 * MB);    // [C][HID]
  short* xq   = (short*)(ws + 24 * MB);
  short* xk   = (short*)(ws + 40 * MB);
  short* xv   = (short*)(ws + 56 * MB);
  short* Qm   = (short*)(ws + 72 * MB);
  short* Km   = (short*)(ws + 88 * MB);
  short* Vm   = (short*)(ws + 104 * MB);
  short* Vt   = (short*)(ws + 120 * MB);
  short* y1   = (short*)(ws + 72 * MB);    // overlays Q/K/V/Vt (dead after attn)
  short* Ob   = xk;                         // overlays xk (dead after K-proj)
  short* hln  = xq;                         // overlays xq (dead after Q-proj)
  float* hbuf = (float*)(ws + 136 * MB);
  (void)ws_size; (void)in_sizes; (void)n_in; (void)out_size;

  dim3 blk(256);
  k_transpose_w<<<dim3(32, 32),  blk, 0, stream>>>(wq, wqT, C, C);
  k_transpose_w<<<dim3(32, 32),  blk, 0, stream>>>(wk, wkT, C, C);
  k_transpose_w<<<dim3(32, 32),  blk, 0, stream>>>(wv, wvT, C, C);
  k_transpose_w<<<dim3(32, 32),  blk, 0, stream>>>(wp, wpT, C, C);
  k_transpose_w<<<dim3(128, 32), blk, 0, stream>>>(w1, w1T, C, HID);
  k_transpose_w<<<dim3(32, 128), blk, 0, stream>>>(w2, w2T, HID, C);
  k_ln_qkv<<<dim3(MTOT), blk, 0, stream>>>(x, pos, nqg, nqb, nkg, nkb, nvg, nvb, xq, xk, xv);
  k_gemm<3><<<dim3(C / 128, MTOT / 128), blk, 0, stream>>>(xq, wqT, bq, nullptr, Qm, C, C);
  k_gemm<0><<<dim3(C / 128, MTOT / 128), blk, 0, stream>>>(xk, wkT, bk, nullptr, Km, C, C);
  k_gemm<0><<<dim3(C / 128, MTOT / 128), blk, 0, stream>>>(xv, wvT, bv, nullptr, Vm, C, C);
  k_transpose_v<<<dim3(SEQ / 32, HD / 32, Bb * NH), blk, 0, stream>>>(Vm, Vt);
  k_attn<<<dim3(Bb * NH, SEQ / 128), blk, 0, stream>>>(Qm, Km, Vt, Ob);
  k_gemm<2><<<dim3(C / 128, MTOT / 128), blk, 0, stream>>>(Ob, wpT, bp, x, hbuf, C, C);
  k_ln1<<<dim3(MTOT), blk, 0, stream>>>(hbuf, ng, nb, hln);
  k_gemm<1><<<dim3(HID / 128, MTOT / 128), blk, 0, stream>>>(hln, w1T, b1, nullptr, y1, HID, C);
  k_gemm<2><<<dim3(C / 128, MTOT / 128), blk, 0, stream>>>(y1, w2T, b2, hbuf, (float*)d_out, C, HID);
}

// Round 5
// 604.134 us; speedup vs baseline: 1.2674x; 1.0249x over previous
//
#include <hip/hip_runtime.h>
#include <hip/hip_bf16.h>

#define DEV __device__ __forceinline__

typedef __attribute__((ext_vector_type(8))) short short8;
typedef __attribute__((ext_vector_type(4))) short short4v;
typedef __attribute__((ext_vector_type(4))) float f32x4;
typedef __attribute__((ext_vector_type(2))) int int2v;

constexpr int Bb   = 4;
constexpr int SEQ  = 2048;
constexpr int C    = 1024;
constexpr int HID  = 4096;
constexpr int NH   = 16;
constexpr int HD   = 64;
constexpr int MTOT = Bb * SEQ;   // 8192 tokens

DEV unsigned bfbits(float f) {
  unsigned x = __float_as_uint(f);
  return (x + 0x7fffu + ((x >> 16) & 1u)) >> 16;   // RNE to bf16, low 16 bits
}

DEV short f2bf(float f) { return (short)bfbits(f); }

// fast bf16 pair pack: +0x8000 (round-half-up, inputs positive finite) + byte perm
DEV unsigned packrn(float a, float b) {
  unsigned ua = __float_as_uint(a) + 0x8000u;
  unsigned ub = __float_as_uint(b) + 0x8000u;
  return __builtin_amdgcn_perm(ub, ua, 0x07060302u);
}

DEV void gload16(const void* g, void* l) {
  __builtin_amdgcn_global_load_lds((const __attribute__((address_space(1))) void*)g,
                                   (__attribute__((address_space(3))) void*)l, 16, 0, 0);
}

// 16x16x16 bf16 MFMA (ISA: v_mfma_f32_16x16x16_bf16, A/B = 2 VGPRs = 4 bf16)
DEV f32x4 mfma16(short4v a, short4v b, f32x4 c) {
#if __has_builtin(__builtin_amdgcn_mfma_f32_16x16x16bf16_1k)
  return __builtin_amdgcn_mfma_f32_16x16x16bf16_1k(a, b, c, 0, 0, 0);
#else
  asm volatile("v_mfma_f32_16x16x16_bf16 %0, %1, %2, %0" : "+v"(c) : "v"(a), "v"(b));
  return c;
#endif
}

// ---------------- weight transpose: fp32 [R][Cc] -> bf16 [Cc][R] ----------------
__global__ void k_transpose_w(const float* __restrict__ src, short* __restrict__ dst,
                              int R, int Cc) {
  __shared__ float t[32][33];
  int tx = threadIdx.x & 31, ty = threadIdx.x >> 5;   // 32 x 8
  int c0 = blockIdx.x * 32, r0 = blockIdx.y * 32;
  #pragma unroll
  for (int i = 0; i < 4; i++)
    t[ty + i * 8][tx] = src[(size_t)(r0 + ty + i * 8) * Cc + c0 + tx];
  __syncthreads();
  #pragma unroll
  for (int i = 0; i < 4; i++)
    dst[(size_t)(c0 + ty + i * 8) * R + r0 + tx] = f2bf(t[tx][ty + i * 8]);
}

// ---------------- V transpose: bf16 [tok][C] -> per-(b,h) [HD][SEQ] ----------------
__global__ void k_transpose_v(const short* __restrict__ V, short* __restrict__ Vt) {
  __shared__ short t[32][33];
  int tx = threadIdx.x & 31, ty = threadIdx.x >> 5;
  int plane = blockIdx.z;                 // b*16 + h
  int b = plane >> 4, h = plane & 15;
  int n0 = blockIdx.x * 32, d0 = blockIdx.y * 32;
  #pragma unroll
  for (int i = 0; i < 4; i++)
    t[ty + i * 8][tx] = V[(size_t)(b * SEQ + n0 + ty + i * 8) * C + h * HD + d0 + tx];
  __syncthreads();
  #pragma unroll
  for (int i = 0; i < 4; i++)
    Vt[((size_t)plane * HD + d0 + ty + i * 8) * SEQ + n0 + tx] = t[tx][ty + i * 8];
}

// ---------------- fused LN for q-input (x) and kv-input (x+pos) ----------------
__global__ void k_ln_qkv(const float* __restrict__ x, const float* __restrict__ pos,
                         const float* __restrict__ nqg, const float* __restrict__ nqb,
                         const float* __restrict__ nkg, const float* __restrict__ nkb,
                         const float* __restrict__ nvg, const float* __restrict__ nvb,
                         short* __restrict__ xq, short* __restrict__ xk,
                         short* __restrict__ xv) {
  int row = blockIdx.x, tid = threadIdx.x;
  int n = row & (SEQ - 1);
  float a4[4], p4[4];
  float s1 = 0, s2 = 0, t1 = 0, t2 = 0;
  #pragma unroll
  for (int i = 0; i < 4; i++) {
    int c = tid + i * 256;
    float a = x[(size_t)row * C + c];
    float p = pos[(size_t)n * C + c] + a;
    a4[i] = a; p4[i] = p;
    s1 += a; s2 += a * a; t1 += p; t2 += p * p;
  }
  #pragma unroll
  for (int off = 32; off; off >>= 1) {
    s1 += __shfl_xor(s1, off, 64);
    s2 += __shfl_xor(s2, off, 64);
    t1 += __shfl_xor(t1, off, 64);
    t2 += __shfl_xor(t2, off, 64);
  }
  __shared__ float red[4][4];
  int wave = tid >> 6, lane = tid & 63;
  if (lane == 0) { red[wave][0] = s1; red[wave][1] = s2; red[wave][2] = t1; red[wave][3] = t2; }
  __syncthreads();
  s1 = red[0][0] + red[1][0] + red[2][0] + red[3][0];
  s2 = red[0][1] + red[1][1] + red[2][1] + red[3][1];
  t1 = red[0][2] + red[1][2] + red[2][2] + red[3][2];
  t2 = red[0][3] + red[1][3] + red[2][3] + red[3][3];
  float mq = s1 * (1.f / C), mk = t1 * (1.f / C);
  float rq = rsqrtf(s2 * (1.f / C) - mq * mq + 1e-5f);
  float rk = rsqrtf(t2 * (1.f / C) - mk * mk + 1e-5f);
  #pragma unroll
  for (int i = 0; i < 4; i++) {
    int c = tid + i * 256;
    float nq_ = (a4[i] - mq) * rq;
    float nk_ = (p4[i] - mk) * rk;
    xq[(size_t)row * C + c] = f2bf(nq_ * nqg[c] + nqb[c]);
    xk[(size_t)row * C + c] = f2bf(nk_ * nkg[c] + nkb[c]);
    xv[(size_t)row * C + c] = f2bf(nk_ * nvg[c] + nvb[c]);
  }
}

// ---------------- plain LN (h -> bf16) ----------------
__global__ void k_ln1(const float* __restrict__ h, const float* __restrict__ g,
                      const float* __restrict__ bta, short* __restrict__ out) {
  int row = blockIdx.x, tid = threadIdx.x;
  float a4[4];
  float s1 = 0, s2 = 0;
  #pragma unroll
  for (int i = 0; i < 4; i++) {
    int c = tid + i * 256;
    float a = h[(size_t)row * C + c];
    a4[i] = a; s1 += a; s2 += a * a;
  }
  #pragma unroll
  for (int off = 32; off; off >>= 1) {
    s1 += __shfl_xor(s1, off, 64);
    s2 += __shfl_xor(s2, off, 64);
  }
  __shared__ float red[4][2];
  int wave = tid >> 6, lane = tid & 63;
  if (lane == 0) { red[wave][0] = s1; red[wave][1] = s2; }
  __syncthreads();
  s1 = red[0][0] + red[1][0] + red[2][0] + red[3][0];
  s2 = red[0][1] + red[1][1] + red[2][1] + red[3][1];
  float m = s1 * (1.f / C);
  float r = rsqrtf(s2 * (1.f / C) - m * m + 1e-5f);
  #pragma unroll
  for (int i = 0; i < 4; i++) {
    int c = tid + i * 256;
    out[(size_t)row * C + c] = f2bf((a4[i] - m) * r * g[c] + bta[c]);
  }
}

// ---------------- GEMM (m97 recipe): global_load_lds staging, unpadded LDS ----------------
// MODE 0: +bias -> bf16;  MODE 1: +bias, LeakyReLU(0.1) -> bf16;
// MODE 2: +bias+resid -> fp32;  MODE 3: (+bias)*0.125*log2e -> bf16 (Q proj, exp2-folded)
template <int MODE>
__global__ __launch_bounds__(256, 2)
void k_gemm(const short* __restrict__ A, const short* __restrict__ Bt,
            const float* __restrict__ bias, const float* __restrict__ resid,
            void* __restrict__ outp, int Nn, int Kk) {
  __shared__ short sA[128 * 32];
  __shared__ short sB[128 * 32];
  const int tid = threadIdx.x;
  const int n0 = blockIdx.x * 128, m0 = blockIdx.y * 128;
  const int wave = tid >> 6, lane = tid & 63, quad = lane >> 4, l15 = lane & 15;
  const int wm = (wave >> 1) * 64, wn = (wave & 1) * 64;

  const int r0 = tid >> 2, s0 = (tid & 3) * 8;
  const short* gA0 = A + (size_t)(m0 + r0) * Kk + s0;
  const short* gA1 = A + (size_t)(m0 + r0 + 64) * Kk + s0;
  const short* gB0 = Bt + (size_t)(n0 + r0) * Kk + s0;
  const short* gB1 = Bt + (size_t)(n0 + r0 + 64) * Kk + s0;
  short* lA0 = &sA[tid * 8];
  short* lA1 = &sA[(tid + 256) * 8];
  short* lB0 = &sB[tid * 8];
  short* lB1 = &sB[(tid + 256) * 8];

  const f32x4 fzero = {0.f, 0.f, 0.f, 0.f};
  f32x4 acc[4][4];
  #pragma unroll
  for (int mi = 0; mi < 4; mi++)
    #pragma unroll
    for (int ni = 0; ni < 4; ni++) acc[mi][ni] = fzero;

  for (int k0 = 0; k0 < Kk; k0 += 32) {
    gload16(gA0 + k0, lA0);
    gload16(gA1 + k0, lA1);
    gload16(gB0 + k0, lB0);
    gload16(gB1 + k0, lB1);
    __syncthreads();
    short8 av[4], bv[4];
    #pragma unroll
    for (int mi = 0; mi < 4; mi++)
      av[mi] = *(const short8*)&sA[(wm + mi * 16 + l15) * 32 + quad * 8];
    #pragma unroll
    for (int ni = 0; ni < 4; ni++)
      bv[ni] = *(const short8*)&sB[(wn + ni * 16 + l15) * 32 + quad * 8];
    #pragma unroll
    for (int mi = 0; mi < 4; mi++)
      #pragma unroll
      for (int ni = 0; ni < 4; ni++)
        acc[mi][ni] = __builtin_amdgcn_mfma_f32_16x16x32_bf16(av[mi], bv[ni], acc[mi][ni], 0, 0, 0);
    __syncthreads();
  }

  float bb[4];
  #pragma unroll
  for (int ni = 0; ni < 4; ni++) bb[ni] = bias[n0 + wn + ni * 16 + l15];

  #pragma unroll
  for (int mi = 0; mi < 4; mi++) {
    #pragma unroll
    for (int ni = 0; ni < 4; ni++) {
      #pragma unroll
      for (int r = 0; r < 4; r++) {
        int row = m0 + wm + mi * 16 + quad * 4 + r;   // C/D layout: row=quad*4+reg
        int col = n0 + wn + ni * 16 + l15;            //             col=lane&15
        float v = acc[mi][ni][r] + bb[ni];
        if constexpr (MODE == 1) v = v >= 0.f ? v : 0.1f * v;
        if constexpr (MODE == 3) v *= 0.1803368801111244f;   // 0.125 * log2(e)
        if constexpr (MODE == 2)
          ((float*)outp)[(size_t)row * Nn + col] = resid[(size_t)row * Nn + col] + v;
        else
          ((short*)outp)[(size_t)row * Nn + col] = f2bf(v);
      }
    }
  }
}

// ---------------- flash attention, S^T formulation, async double-buffered K/V ----------------
// S^T C-layout (key=quad*4+r, q=l15) IS the 16x16x16 A-operand layout (m=l15, k=quad*4+j),
// so PV runs on mfma_16x16x16 with the packed exp2 results as A directly — no cross-lane
// transpose. Row-sums via MFMA with a ones-B (lands in C-layout, same indexing as O).
__global__ __launch_bounds__(256, 4)
void k_attn(const short* __restrict__ Q, const short* __restrict__ K,
            const short* __restrict__ Vt, short* __restrict__ O) {
  __shared__ __align__(16) short sK[2][64 * 64];
  __shared__ __align__(16) short sV[2][64 * 64];   // Vt tile: [d][key]
  const int tid = threadIdx.x;
  const int bh = blockIdx.x;                        // bh fastest -> XCD-pinned K/V reuse
  const int b = bh >> 4, h = bh & 15;
  const int q0 = blockIdx.y * 128;
  const int wave = tid >> 6, lane = tid & 63, quad = lane >> 4, l15 = lane & 15;
  const int wm = wave * 32;        // 32 q-rows per wave
  const size_t tokBase = (size_t)b * SEQ;

  // Q fragments in registers (B-operand of QK^T): [qi][d-half]
  short8 qf[2][2];
  #pragma unroll
  for (int qi = 0; qi < 2; qi++)
    #pragma unroll
    for (int hf = 0; hf < 2; hf++)
      qf[qi][hf] = *(const short8*)(Q + (tokBase + q0 + wm + qi * 16 + l15) * C
                                    + h * HD + hf * 32 + quad * 8);

  // staging: 2 slots/thread/array; store global seg (slot&7)^(row&7) at phys seg slot&7
  const int r0 = tid >> 3,        c0s = ((tid & 7) ^ (r0 & 7)) * 8;
  const int r1 = (tid + 256) >> 3, c1s = ((tid & 7) ^ (r1 & 7)) * 8;
  const short* gK0 = K + (tokBase + r0) * C + h * HD + c0s;
  const short* gK1 = K + (tokBase + r1) * C + h * HD + c1s;
  const short* gV0 = Vt + ((size_t)bh * HD + r0) * SEQ + c0s;
  const short* gV1 = Vt + ((size_t)bh * HD + r1) * SEQ + c1s;
  short* lK0 = &sK[0][tid * 8];
  short* lK1 = &sK[0][(tid + 256) * 8];
  short* lV0 = &sV[0][tid * 8];
  short* lV1 = &sV[0][(tid + 256) * 8];
  constexpr int BUFO = 64 * 64;   // shorts per buffer

#define STAGE(bufsel, kb) {                                   \
    int kk = (kb) * 64, bo = (bufsel) * BUFO;                 \
    gload16(gK0 + (size_t)kk * C, lK0 + bo);                  \
    gload16(gK1 + (size_t)kk * C, lK1 + bo);                  \
    gload16(gV0 + kk,             lV0 + bo);                  \
    gload16(gV1 + kk,             lV1 + bo); }

  const f32x4 fzero = {0.f, 0.f, 0.f, 0.f};
  const short4v onesv = {0x3F80, 0x3F80, 0x3F80, 0x3F80};   // bf16 1.0 x4
  f32x4 o[2][4];
  f32x4 oSum[2] = {fzero, fzero};
  #pragma unroll
  for (int qi = 0; qi < 2; qi++)
    #pragma unroll
    for (int di = 0; di < 4; di++) o[qi][di] = fzero;

  const int sw = l15 & 7;                    // seg swizzle key

  STAGE(0, 0)

  for (int kb = 0; kb < SEQ / 64; kb++) {
    const int buf = kb & 1;
    __syncthreads();                         // drains prefetch vmcnt; guards buf reuse
    if (kb + 1 < SEQ / 64) STAGE(buf ^ 1, kb + 1)

    // S^T tiles: D[key][q], key=quad*4+r (within ki*16), q=l15; exp2 + pack immediately.
    // pk[ki][qi][0..1] = packed P row fragment == x16 A-operand.
    unsigned pk[4][2][2];
    #pragma unroll
    for (int ki = 0; ki < 4; ki++) {
      const int krow = (ki * 16 + l15) * 64;
      short8 a0 = *(const short8*)&sK[buf][krow + ((0 + quad) ^ sw) * 8];
      short8 a1 = *(const short8*)&sK[buf][krow + ((4 + quad) ^ sw) * 8];
      #pragma unroll
      for (int qi = 0; qi < 2; qi++) {
        f32x4 st = __builtin_amdgcn_mfma_f32_16x16x32_bf16(a0, qf[qi][0], fzero, 0, 0, 0);
        st = __builtin_amdgcn_mfma_f32_16x16x32_bf16(a1, qf[qi][1], st, 0, 0, 0);
        float p0 = exp2f(st[0]), p1 = exp2f(st[1]);
        float p2 = exp2f(st[2]), p3 = exp2f(st[3]);
        pk[ki][qi][0] = packrn(p0, p1);
        pk[ki][qi][1] = packrn(p2, p3);
      }
    }

    // PV + row-sum, all on 16x16x16 MFMA; V B-fragment = 4 consecutive keys (b64 read)
    #pragma unroll
    for (int ki = 0; ki < 4; ki++) {
      short4v bv[4];
      const int g = ((ki * 2 + (quad >> 1)) ^ sw) * 8 + (quad & 1) * 4;
      #pragma unroll
      for (int di = 0; di < 4; di++)
        bv[di] = *(const short4v*)&sV[buf][(di * 16 + l15) * 64 + g];
      #pragma unroll
      for (int qi = 0; qi < 2; qi++) {
        int2v t; t.x = (int)pk[ki][qi][0]; t.y = (int)pk[ki][qi][1];
        short4v aP = __builtin_bit_cast(short4v, t);
        oSum[qi] = mfma16(aP, onesv, oSum[qi]);
        #pragma unroll
        for (int di = 0; di < 4; di++)
          o[qi][di] = mfma16(aP, bv[di], o[qi][di]);
      }
    }
  }
#undef STAGE

  // oSum C-layout row=quad*4+r holds the softmax denom for that q — same indexing as o
  float linv[2][4];
  #pragma unroll
  for (int qi = 0; qi < 2; qi++)
    #pragma unroll
    for (int r = 0; r < 4; r++)
      linv[qi][r] = 1.0f / oSum[qi][r];

  #pragma unroll
  for (int qi = 0; qi < 2; qi++)
    #pragma unroll
    for (int di = 0; di < 4; di++)
      #pragma unroll
      for (int r = 0; r < 4; r++) {
        int row = q0 + wm + qi * 16 + quad * 4 + r;
        int col = h * HD + di * 16 + l15;
        O[(tokBase + row) * C + col] = f2bf(o[qi][di][r] * linv[qi][r]);
      }
}

extern "C" void kernel_launch(void* const* d_in, const int* in_sizes, int n_in,
                              void* d_out, int out_size, void* d_ws, size_t ws_size,
                              hipStream_t stream) {
  const float* x   = (const float*)d_in[0];
  const float* pos = (const float*)d_in[1];
  const float* nqg = (const float*)d_in[2];
  const float* nqb = (const float*)d_in[3];
  const float* nkg = (const float*)d_in[4];
  const float* nkb = (const float*)d_in[5];
  const float* nvg = (const float*)d_in[6];
  const float* nvb = (const float*)d_in[7];
  const float* ng  = (const float*)d_in[8];
  const float* nb  = (const float*)d_in[9];
  const float* wq  = (const float*)d_in[10];
  const float* bq  = (const float*)d_in[11];
  const float* wk  = (const float*)d_in[12];
  const float* bk  = (const float*)d_in[13];
  const float* wv  = (const float*)d_in[14];
  const float* bv  = (const float*)d_in[15];
  const float* wp  = (const float*)d_in[16];
  const float* bp  = (const float*)d_in[17];
  const float* w1  = (const float*)d_in[18];
  const float* b1  = (const float*)d_in[19];
  const float* w2  = (const float*)d_in[20];
  const float* b2  = (const float*)d_in[21];

  char* ws = (char*)d_ws;
  const size_t MB = 1u << 20;
  short* wqT  = (short*)(ws + 0 * MB);
  short* wkT  = (short*)(ws + 2 * MB);
  short* wvT  = (short*)(ws + 4 * MB);
  short* wpT  = (short*)(ws + 6 * MB);
  short* w1T  = (short*)(ws + 8 * MB);     // [HID][C]
  short* w2T  = (short*)(ws + 16 * MB);    // [C][HID]
  short* xq   = (short*)(ws + 24 * MB);
  short* xk   = (short*)(ws + 40 * MB);
  short* xv   = (short*)(ws + 56 * MB);
  short* Qm   = (short*)(ws + 72 * MB);
  short* Km   = (short*)(ws + 88 * MB);
  short* Vm   = (short*)(ws + 104 * MB);
  short* Vt   = (short*)(ws + 120 * MB);
  short* y1   = (short*)(ws + 72 * MB);    // overlays Q/K/V/Vt (dead after attn)
  short* Ob   = xk;                         // overlays xk (dead after K-proj)
  short* hln  = xq;                         // overlays xq (dead after Q-proj)
  float* hbuf = (float*)(ws + 136 * MB);
  (void)ws_size; (void)in_sizes; (void)n_in; (void)out_size;

  dim3 blk(256);
  k_transpose_w<<<dim3(32, 32),  blk, 0, stream>>>(wq, wqT, C, C);
  k_transpose_w<<<dim3(32, 32),  blk, 0, stream>>>(wk, wkT, C, C);
  k_transpose_w<<<dim3(32, 32),  blk, 0, stream>>>(wv, wvT, C, C);
  k_transpose_w<<<dim3(32, 32),  blk, 0, stream>>>(wp, wpT, C, C);
  k_transpose_w<<<dim3(128, 32), blk, 0, stream>>>(w1, w1T, C, HID);
  k_transpose_w<<<dim3(32, 128), blk, 0, stream>>>(w2, w2T, HID, C);
  k_ln_qkv<<<dim3(MTOT), blk, 0, stream>>>(x, pos, nqg, nqb, nkg, nkb, nvg, nvb, xq, xk, xv);
  k_gemm<3><<<dim3(C / 128, MTOT / 128), blk, 0, stream>>>(xq, wqT, bq, nullptr, Qm, C, C);
  k_gemm<0><<<dim3(C / 128, MTOT / 128), blk, 0, stream>>>(xk, wkT, bk, nullptr, Km, C, C);
  k_gemm<0><<<dim3(C / 128, MTOT / 128), blk, 0, stream>>>(xv, wvT, bv, nullptr, Vm, C, C);
  k_transpose_v<<<dim3(SEQ / 32, HD / 32, Bb * NH), blk, 0, stream>>>(Vm, Vt);
  k_attn<<<dim3(Bb * NH, SEQ / 128), blk, 0, stream>>>(Qm, Km, Vt, Ob);
  k_gemm<2><<<dim3(C / 128, MTOT / 128), blk, 0, stream>>>(Ob, wpT, bp, x, hbuf, C, C);
  k_ln1<<<dim3(MTOT), blk, 0, stream>>>(hbuf, ng, nb, hln);
  k_gemm<1><<<dim3(HID / 128, MTOT / 128), blk, 0, stream>>>(hln, w1T, b1, nullptr, y1, HID, C);
  k_gemm<2><<<dim3(C / 128, MTOT / 128), blk, 0, stream>>>(y1, w2T, b2, hbuf, (float*)d_out, C, HID);
}

// Round 6
// 569.293 us; speedup vs baseline: 1.3450x; 1.0612x over previous
//
#include <hip/hip_runtime.h>
#include <hip/hip_bf16.h>

#define DEV __device__ __forceinline__

typedef __attribute__((ext_vector_type(8))) short short8;
typedef __attribute__((ext_vector_type(4))) short short4v;
typedef __attribute__((ext_vector_type(4))) float f32x4;
typedef __attribute__((ext_vector_type(2))) int int2v;

constexpr int Bb   = 4;
constexpr int SEQ  = 2048;
constexpr int C    = 1024;
constexpr int HID  = 4096;
constexpr int NH   = 16;
constexpr int HD   = 64;
constexpr int MTOT = Bb * SEQ;   // 8192 tokens

DEV unsigned bfbits(float f) {
  unsigned x = __float_as_uint(f);
  return (x + 0x7fffu + ((x >> 16) & 1u)) >> 16;   // RNE to bf16, low 16 bits
}

DEV short f2bf(float f) { return (short)bfbits(f); }

// fast bf16 pair pack: +0x8000 (round-half-up, inputs positive finite) + byte perm
DEV unsigned packrn(float a, float b) {
  unsigned ua = __float_as_uint(a) + 0x8000u;
  unsigned ub = __float_as_uint(b) + 0x8000u;
  return __builtin_amdgcn_perm(ub, ua, 0x07060302u);
}

// raw v_exp_f32 (2^x), no OCML denorm guard (flush-to-zero fine for softmax)
DEV float fexp2(float x) {
#if __has_builtin(__builtin_amdgcn_exp2f)
  return __builtin_amdgcn_exp2f(x);
#else
  float r;
  asm("v_exp_f32 %0, %1" : "=v"(r) : "v"(x));
  return r;
#endif
}

DEV void gload16(const void* g, void* l) {
  __builtin_amdgcn_global_load_lds((const __attribute__((address_space(1))) void*)g,
                                   (__attribute__((address_space(3))) void*)l, 16, 0, 0);
}

// 16x16x16 bf16 MFMA (A/B = 2 VGPRs = 4 bf16)
DEV f32x4 mfma16(short4v a, short4v b, f32x4 c) {
#if __has_builtin(__builtin_amdgcn_mfma_f32_16x16x16bf16_1k)
  return __builtin_amdgcn_mfma_f32_16x16x16bf16_1k(a, b, c, 0, 0, 0);
#else
  asm volatile("v_mfma_f32_16x16x16_bf16 %0, %1, %2, %0" : "+v"(c) : "v"(a), "v"(b));
  return c;
#endif
}

// ---------------- weight transpose: fp32 [R][Cc] -> bf16 [Cc][R] ----------------
DEV void transpose_body(const float* __restrict__ src, short* __restrict__ dst,
                        int R, int Cc) {
  __shared__ float t[32][33];
  int tx = threadIdx.x & 31, ty = threadIdx.x >> 5;   // 32 x 8
  int c0 = blockIdx.x * 32, r0 = blockIdx.y * 32;
  #pragma unroll
  for (int i = 0; i < 4; i++)
    t[ty + i * 8][tx] = src[(size_t)(r0 + ty + i * 8) * Cc + c0 + tx];
  __syncthreads();
  #pragma unroll
  for (int i = 0; i < 4; i++)
    dst[(size_t)(c0 + ty + i * 8) * R + r0 + tx] = f2bf(t[tx][ty + i * 8]);
}

__global__ void k_transpose_w(const float* __restrict__ src, short* __restrict__ dst,
                              int R, int Cc) {
  transpose_body(src, dst, R, Cc);
}

// 4 square CxC transposes in one launch (z selects)
__global__ void k_transpose_w4(const float* __restrict__ s0, const float* __restrict__ s1,
                               const float* __restrict__ s2, const float* __restrict__ s3,
                               short* __restrict__ d0, short* __restrict__ d1,
                               short* __restrict__ d2, short* __restrict__ d3) {
  const float* s = blockIdx.z == 0 ? s0 : blockIdx.z == 1 ? s1 : blockIdx.z == 2 ? s2 : s3;
  short*       d = blockIdx.z == 0 ? d0 : blockIdx.z == 1 ? d1 : blockIdx.z == 2 ? d2 : d3;
  transpose_body(s, d, C, C);
}

// ---------------- V transpose: bf16 [tok][C] -> per-(b,h) [HD][SEQ] ----------------
__global__ void k_transpose_v(const short* __restrict__ V, short* __restrict__ Vt) {
  __shared__ short t[32][33];
  int tx = threadIdx.x & 31, ty = threadIdx.x >> 5;
  int plane = blockIdx.z;                 // b*16 + h
  int b = plane >> 4, h = plane & 15;
  int n0 = blockIdx.x * 32, d0 = blockIdx.y * 32;
  #pragma unroll
  for (int i = 0; i < 4; i++)
    t[ty + i * 8][tx] = V[(size_t)(b * SEQ + n0 + ty + i * 8) * C + h * HD + d0 + tx];
  __syncthreads();
  #pragma unroll
  for (int i = 0; i < 4; i++)
    Vt[((size_t)plane * HD + d0 + ty + i * 8) * SEQ + n0 + tx] = t[tx][ty + i * 8];
}

// ---------------- fused LN for q-input (x) and kv-input (x+pos) ----------------
__global__ void k_ln_qkv(const float* __restrict__ x, const float* __restrict__ pos,
                         const float* __restrict__ nqg, const float* __restrict__ nqb,
                         const float* __restrict__ nkg, const float* __restrict__ nkb,
                         const float* __restrict__ nvg, const float* __restrict__ nvb,
                         short* __restrict__ xq, short* __restrict__ xk,
                         short* __restrict__ xv) {
  int row = blockIdx.x, tid = threadIdx.x;
  int n = row & (SEQ - 1);
  float a4[4], p4[4];
  float s1 = 0, s2 = 0, t1 = 0, t2 = 0;
  #pragma unroll
  for (int i = 0; i < 4; i++) {
    int c = tid + i * 256;
    float a = x[(size_t)row * C + c];
    float p = pos[(size_t)n * C + c] + a;
    a4[i] = a; p4[i] = p;
    s1 += a; s2 += a * a; t1 += p; t2 += p * p;
  }
  #pragma unroll
  for (int off = 32; off; off >>= 1) {
    s1 += __shfl_xor(s1, off, 64);
    s2 += __shfl_xor(s2, off, 64);
    t1 += __shfl_xor(t1, off, 64);
    t2 += __shfl_xor(t2, off, 64);
  }
  __shared__ float red[4][4];
  int wave = tid >> 6, lane = tid & 63;
  if (lane == 0) { red[wave][0] = s1; red[wave][1] = s2; red[wave][2] = t1; red[wave][3] = t2; }
  __syncthreads();
  s1 = red[0][0] + red[1][0] + red[2][0] + red[3][0];
  s2 = red[0][1] + red[1][1] + red[2][1] + red[3][1];
  t1 = red[0][2] + red[1][2] + red[2][2] + red[3][2];
  t2 = red[0][3] + red[1][3] + red[2][3] + red[3][3];
  float mq = s1 * (1.f / C), mk = t1 * (1.f / C);
  float rq = rsqrtf(s2 * (1.f / C) - mq * mq + 1e-5f);
  float rk = rsqrtf(t2 * (1.f / C) - mk * mk + 1e-5f);
  #pragma unroll
  for (int i = 0; i < 4; i++) {
    int c = tid + i * 256;
    float nq_ = (a4[i] - mq) * rq;
    float nk_ = (p4[i] - mk) * rk;
    xq[(size_t)row * C + c] = f2bf(nq_ * nqg[c] + nqb[c]);
    xk[(size_t)row * C + c] = f2bf(nk_ * nkg[c] + nkb[c]);
    xv[(size_t)row * C + c] = f2bf(nk_ * nvg[c] + nvb[c]);
  }
}

// ---------------- plain LN (h -> bf16) ----------------
__global__ void k_ln1(const float* __restrict__ h, const float* __restrict__ g,
                      const float* __restrict__ bta, short* __restrict__ out) {
  int row = blockIdx.x, tid = threadIdx.x;
  float a4[4];
  float s1 = 0, s2 = 0;
  #pragma unroll
  for (int i = 0; i < 4; i++) {
    int c = tid + i * 256;
    float a = h[(size_t)row * C + c];
    a4[i] = a; s1 += a; s2 += a * a;
  }
  #pragma unroll
  for (int off = 32; off; off >>= 1) {
    s1 += __shfl_xor(s1, off, 64);
    s2 += __shfl_xor(s2, off, 64);
  }
  __shared__ float red[4][2];
  int wave = tid >> 6, lane = tid & 63;
  if (lane == 0) { red[wave][0] = s1; red[wave][1] = s2; }
  __syncthreads();
  s1 = red[0][0] + red[1][0] + red[2][0] + red[3][0];
  s2 = red[0][1] + red[1][1] + red[2][1] + red[3][1];
  float m = s1 * (1.f / C);
  float r = rsqrtf(s2 * (1.f / C) - m * m + 1e-5f);
  #pragma unroll
  for (int i = 0; i < 4; i++) {
    int c = tid + i * 256;
    out[(size_t)row * C + c] = f2bf((a4[i] - m) * r * g[c] + bta[c]);
  }
}

// ---------------- GEMM core (m97 recipe): global_load_lds staging, unpadded LDS -------
// Computes acc = A[128 rows] @ Bt[128 rows]^T over K, returns in caller's acc[4][4].
struct GemmCore {
  f32x4 acc[4][4];
};

template <typename EPI>
DEV void gemm_body(const short* __restrict__ A, const short* __restrict__ Bt,
                   int Kk, short* sA, short* sB, EPI&& epi) {
  const int tid = threadIdx.x;
  const int wave = tid >> 6, lane = tid & 63, quad = lane >> 4, l15 = lane & 15;
  const int wm = (wave >> 1) * 64, wn = (wave & 1) * 64;

  const int r0 = tid >> 2, s0 = (tid & 3) * 8;
  const short* gA0 = A + (size_t)r0 * Kk + s0;
  const short* gA1 = A + (size_t)(r0 + 64) * Kk + s0;
  const short* gB0 = Bt + (size_t)r0 * Kk + s0;
  const short* gB1 = Bt + (size_t)(r0 + 64) * Kk + s0;
  short* lA0 = &sA[tid * 8];
  short* lA1 = &sA[(tid + 256) * 8];
  short* lB0 = &sB[tid * 8];
  short* lB1 = &sB[(tid + 256) * 8];

  const f32x4 fzero = {0.f, 0.f, 0.f, 0.f};
  f32x4 acc[4][4];
  #pragma unroll
  for (int mi = 0; mi < 4; mi++)
    #pragma unroll
    for (int ni = 0; ni < 4; ni++) acc[mi][ni] = fzero;

  for (int k0 = 0; k0 < Kk; k0 += 32) {
    gload16(gA0 + k0, lA0);
    gload16(gA1 + k0, lA1);
    gload16(gB0 + k0, lB0);
    gload16(gB1 + k0, lB1);
    __syncthreads();
    short8 av[4], bv[4];
    #pragma unroll
    for (int mi = 0; mi < 4; mi++)
      av[mi] = *(const short8*)&sA[(wm + mi * 16 + l15) * 32 + quad * 8];
    #pragma unroll
    for (int ni = 0; ni < 4; ni++)
      bv[ni] = *(const short8*)&sB[(wn + ni * 16 + l15) * 32 + quad * 8];
    #pragma unroll
    for (int mi = 0; mi < 4; mi++)
      #pragma unroll
      for (int ni = 0; ni < 4; ni++)
        acc[mi][ni] = __builtin_amdgcn_mfma_f32_16x16x32_bf16(av[mi], bv[ni], acc[mi][ni], 0, 0, 0);
    __syncthreads();
  }
  epi(acc, wm, wn, quad, l15);
}

// MODE 0: +bias -> bf16;  MODE 1: +bias, LeakyReLU(0.1) -> bf16;  MODE 2: +bias+resid -> fp32
template <int MODE>
__global__ __launch_bounds__(256, 2)
void k_gemm(const short* __restrict__ A, const short* __restrict__ Bt,
            const float* __restrict__ bias, const float* __restrict__ resid,
            void* __restrict__ outp, int Nn, int Kk) {
  __shared__ short sA[128 * 32];
  __shared__ short sB[128 * 32];
  const int n0 = blockIdx.x * 128, m0 = blockIdx.y * 128;
  gemm_body(A + (size_t)m0 * Kk, Bt + (size_t)n0 * Kk, Kk, sA, sB,
    [&](f32x4 (&acc)[4][4], int wm, int wn, int quad, int l15) {
      float bb[4];
      #pragma unroll
      for (int ni = 0; ni < 4; ni++) bb[ni] = bias[n0 + wn + ni * 16 + l15];
      #pragma unroll
      for (int mi = 0; mi < 4; mi++) {
        #pragma unroll
        for (int ni = 0; ni < 4; ni++) {
          #pragma unroll
          for (int r = 0; r < 4; r++) {
            int row = m0 + wm + mi * 16 + quad * 4 + r;   // C/D: row=quad*4+reg
            int col = n0 + wn + ni * 16 + l15;            //      col=lane&15
            float v = acc[mi][ni][r] + bb[ni];
            if constexpr (MODE == 1) v = v >= 0.f ? v : 0.1f * v;
            if constexpr (MODE == 2)
              ((float*)outp)[(size_t)row * Nn + col] = resid[(size_t)row * Nn + col] + v;
            else
              ((short*)outp)[(size_t)row * Nn + col] = f2bf(v);
          }
        }
      }
    });
}

// fused QKV projection: z selects {xq->Qm (scaled), xk->Km, xv->Vm}
__global__ __launch_bounds__(256, 2)
void k_gemm_qkv(const short* __restrict__ xq, const short* __restrict__ xk,
                const short* __restrict__ xv,
                const short* __restrict__ wqT, const short* __restrict__ wkT,
                const short* __restrict__ wvT,
                const float* __restrict__ bq, const float* __restrict__ bk,
                const float* __restrict__ bv,
                short* __restrict__ Qm, short* __restrict__ Km, short* __restrict__ Vm) {
  __shared__ short sA[128 * 32];
  __shared__ short sB[128 * 32];
  const int z = blockIdx.z;
  const short* A    = z == 0 ? xq : z == 1 ? xk : xv;
  const short* Bt   = z == 0 ? wqT : z == 1 ? wkT : wvT;
  const float* bias = z == 0 ? bq : z == 1 ? bk : bv;
  short* outp       = z == 0 ? Qm : z == 1 ? Km : Vm;
  const float scale = z == 0 ? 0.1803368801111244f : 1.0f;   // 0.125 * log2(e) on Q
  const int n0 = blockIdx.x * 128, m0 = blockIdx.y * 128;
  gemm_body(A + (size_t)m0 * C, Bt + (size_t)n0 * C, C, sA, sB,
    [&](f32x4 (&acc)[4][4], int wm, int wn, int quad, int l15) {
      float bb[4];
      #pragma unroll
      for (int ni = 0; ni < 4; ni++) bb[ni] = bias[n0 + wn + ni * 16 + l15];
      #pragma unroll
      for (int mi = 0; mi < 4; mi++)
        #pragma unroll
        for (int ni = 0; ni < 4; ni++)
          #pragma unroll
          for (int r = 0; r < 4; r++) {
            int row = m0 + wm + mi * 16 + quad * 4 + r;
            int col = n0 + wn + ni * 16 + l15;
            outp[(size_t)row * C + col] = f2bf((acc[mi][ni][r] + bb[ni]) * scale);
          }
    });
}

// ---------------- flash attention, S^T formulation, async double-buffered K/V ----------------
// S^T C-layout (key=quad*4+r, q=l15) IS the 16x16x16 A-operand layout (m=l15, k=quad*4+j),
// so PV runs on mfma_16x16x16 with the packed exp2 results as A directly. Row-sums via
// MFMA with a ones-B (lands in C-layout, same indexing as O).
__global__ __launch_bounds__(256, 4)
void k_attn(const short* __restrict__ Q, const short* __restrict__ K,
            const short* __restrict__ Vt, short* __restrict__ O) {
  __shared__ __align__(16) short sK[2][64 * 64];
  __shared__ __align__(16) short sV[2][64 * 64];   // Vt tile: [d][key]
  const int tid = threadIdx.x;
  const int bh = blockIdx.x;                        // bh fastest -> XCD-pinned K/V reuse
  const int b = bh >> 4, h = bh & 15;
  const int q0 = blockIdx.y * 128;
  const int wave = tid >> 6, lane = tid & 63, quad = lane >> 4, l15 = lane & 15;
  const int wm = wave * 32;        // 32 q-rows per wave
  const size_t tokBase = (size_t)b * SEQ;

  // Q fragments in registers (B-operand of QK^T): [qi][d-half]
  short8 qf[2][2];
  #pragma unroll
  for (int qi = 0; qi < 2; qi++)
    #pragma unroll
    for (int hf = 0; hf < 2; hf++)
      qf[qi][hf] = *(const short8*)(Q + (tokBase + q0 + wm + qi * 16 + l15) * C
                                    + h * HD + hf * 32 + quad * 8);

  // staging: 2 slots/thread/array; store global seg (slot&7)^(row&7) at phys seg slot&7
  const int r0 = tid >> 3,        c0s = ((tid & 7) ^ (r0 & 7)) * 8;
  const int r1 = (tid + 256) >> 3, c1s = ((tid & 7) ^ (r1 & 7)) * 8;
  const short* gK0 = K + (tokBase + r0) * C + h * HD + c0s;
  const short* gK1 = K + (tokBase + r1) * C + h * HD + c1s;
  const short* gV0 = Vt + ((size_t)bh * HD + r0) * SEQ + c0s;
  const short* gV1 = Vt + ((size_t)bh * HD + r1) * SEQ + c1s;
  short* lK0 = &sK[0][tid * 8];
  short* lK1 = &sK[0][(tid + 256) * 8];
  short* lV0 = &sV[0][tid * 8];
  short* lV1 = &sV[0][(tid + 256) * 8];
  constexpr int BUFO = 64 * 64;   // shorts per buffer

#define STAGE(bufsel, kb) {                                   \
    int kk = (kb) * 64, bo = (bufsel) * BUFO;                 \
    gload16(gK0 + (size_t)kk * C, lK0 + bo);                  \
    gload16(gK1 + (size_t)kk * C, lK1 + bo);                  \
    gload16(gV0 + kk,             lV0 + bo);                  \
    gload16(gV1 + kk,             lV1 + bo); }

  const f32x4 fzero = {0.f, 0.f, 0.f, 0.f};
  const short4v onesv = {0x3F80, 0x3F80, 0x3F80, 0x3F80};   // bf16 1.0 x4
  f32x4 o[2][4];
  f32x4 oSum[2] = {fzero, fzero};
  #pragma unroll
  for (int qi = 0; qi < 2; qi++)
    #pragma unroll
    for (int di = 0; di < 4; di++) o[qi][di] = fzero;

  const int sw = l15 & 7;                    // seg swizzle key

  STAGE(0, 0)

  for (int kb = 0; kb < SEQ / 64; kb++) {
    const int buf = kb & 1;
    __syncthreads();                         // drains prefetch vmcnt; guards buf reuse
    if (kb + 1 < SEQ / 64) STAGE(buf ^ 1, kb + 1)

    // S^T tiles: D[key][q], key=quad*4+r (within ki*16), q=l15; exp2 + pack immediately.
    // pk[ki][qi][0..1] = packed P row fragment == x16 A-operand.
    unsigned pk[4][2][2];
    #pragma unroll
    for (int ki = 0; ki < 4; ki++) {
      const int krow = (ki * 16 + l15) * 64;
      short8 a0 = *(const short8*)&sK[buf][krow + ((0 + quad) ^ sw) * 8];
      short8 a1 = *(const short8*)&sK[buf][krow + ((4 + quad) ^ sw) * 8];
      #pragma unroll
      for (int qi = 0; qi < 2; qi++) {
        f32x4 st = __builtin_amdgcn_mfma_f32_16x16x32_bf16(a0, qf[qi][0], fzero, 0, 0, 0);
        st = __builtin_amdgcn_mfma_f32_16x16x32_bf16(a1, qf[qi][1], st, 0, 0, 0);
        float p0 = fexp2(st[0]), p1 = fexp2(st[1]);
        float p2 = fexp2(st[2]), p3 = fexp2(st[3]);
        pk[ki][qi][0] = packrn(p0, p1);
        pk[ki][qi][1] = packrn(p2, p3);
      }
    }

    // PV + row-sum, all on 16x16x16 MFMA; V B-fragment = 4 consecutive keys (b64 read)
    #pragma unroll
    for (int ki = 0; ki < 4; ki++) {
      short4v bv[4];
      const int g = ((ki * 2 + (quad >> 1)) ^ sw) * 8 + (quad & 1) * 4;
      #pragma unroll
      for (int di = 0; di < 4; di++)
        bv[di] = *(const short4v*)&sV[buf][(di * 16 + l15) * 64 + g];
      #pragma unroll
      for (int qi = 0; qi < 2; qi++) {
        int2v t; t.x = (int)pk[ki][qi][0]; t.y = (int)pk[ki][qi][1];
        short4v aP = __builtin_bit_cast(short4v, t);
        oSum[qi] = mfma16(aP, onesv, oSum[qi]);
        #pragma unroll
        for (int di = 0; di < 4; di++)
          o[qi][di] = mfma16(aP, bv[di], o[qi][di]);
      }
    }
  }
#undef STAGE

  // oSum C-layout row=quad*4+r holds the softmax denom for that q — same indexing as o
  float linv[2][4];
  #pragma unroll
  for (int qi = 0; qi < 2; qi++)
    #pragma unroll
    for (int r = 0; r < 4; r++)
      linv[qi][r] = 1.0f / oSum[qi][r];

  #pragma unroll
  for (int qi = 0; qi < 2; qi++)
    #pragma unroll
    for (int di = 0; di < 4; di++)
      #pragma unroll
      for (int r = 0; r < 4; r++) {
        int row = q0 + wm + qi * 16 + quad * 4 + r;
        int col = h * HD + di * 16 + l15;
        O[(tokBase + row) * C + col] = f2bf(o[qi][di][r] * linv[qi][r]);
      }
}

extern "C" void kernel_launch(void* const* d_in, const int* in_sizes, int n_in,
                              void* d_out, int out_size, void* d_ws, size_t ws_size,
                              hipStream_t stream) {
  const float* x   = (const float*)d_in[0];
  const float* pos = (const float*)d_in[1];
  const float* nqg = (const float*)d_in[2];
  const float* nqb = (const float*)d_in[3];
  const float* nkg = (const float*)d_in[4];
  const float* nkb = (const float*)d_in[5];
  const float* nvg = (const float*)d_in[6];
  const float* nvb = (const float*)d_in[7];
  const float* ng  = (const float*)d_in[8];
  const float* nb  = (const float*)d_in[9];
  const float* wq  = (const float*)d_in[10];
  const float* bq  = (const float*)d_in[11];
  const float* wk  = (const float*)d_in[12];
  const float* bk  = (const float*)d_in[13];
  const float* wv  = (const float*)d_in[14];
  const float* bv  = (const float*)d_in[15];
  const float* wp  = (const float*)d_in[16];
  const float* bp  = (const float*)d_in[17];
  const float* w1  = (const float*)d_in[18];
  const float* b1  = (const float*)d_in[19];
  const float* w2  = (const float*)d_in[20];
  const float* b2  = (const float*)d_in[21];

  char* ws = (char*)d_ws;
  const size_t MB = 1u << 20;
  short* wqT  = (short*)(ws + 0 * MB);
  short* wkT  = (short*)(ws + 2 * MB);
  short* wvT  = (short*)(ws + 4 * MB);
  short* wpT  = (short*)(ws + 6 * MB);
  short* w1T  = (short*)(ws + 8 * MB);     // [HID][C]
  short* w2T  = (short*)(ws + 16 * MB);    // [C][HID]
  short* xq   = (short*)(ws + 24 * MB);
  short* xk   = (short*)(ws + 40 * MB);
  short* xv   = (short*)(ws + 56 * MB);
  short* Qm   = (short*)(ws + 72 * MB);
  short* Km   = (short*)(ws + 88 * MB);
  short* Vm   = (short*)(ws + 104 * MB);
  short* Vt   = (short*)(ws + 120 * MB);
  short* y1   = (short*)(ws + 72 * MB);    // overlays Q/K/V/Vt (dead after attn)
  short* Ob   = xk;                         // overlays xk (dead after K-proj)
  short* hln  = xq;                         // overlays xq (dead after Q-proj)
  float* hbuf = (float*)(ws + 136 * MB);
  (void)ws_size; (void)in_sizes; (void)n_in; (void)out_size;

  dim3 blk(256);
  k_transpose_w4<<<dim3(32, 32, 4), blk, 0, stream>>>(wq, wk, wv, wp, wqT, wkT, wvT, wpT);
  k_transpose_w<<<dim3(128, 32), blk, 0, stream>>>(w1, w1T, C, HID);
  k_transpose_w<<<dim3(32, 128), blk, 0, stream>>>(w2, w2T, HID, C);
  k_ln_qkv<<<dim3(MTOT), blk, 0, stream>>>(x, pos, nqg, nqb, nkg, nkb, nvg, nvb, xq, xk, xv);
  k_gemm_qkv<<<dim3(C / 128, MTOT / 128, 3), blk, 0, stream>>>(xq, xk, xv, wqT, wkT, wvT,
                                                               bq, bk, bv, Qm, Km, Vm);
  k_transpose_v<<<dim3(SEQ / 32, HD / 32, Bb * NH), blk, 0, stream>>>(Vm, Vt);
  k_attn<<<dim3(Bb * NH, SEQ / 128), blk, 0, stream>>>(Qm, Km, Vt, Ob);
  k_gemm<2><<<dim3(C / 128, MTOT / 128), blk, 0, stream>>>(Ob, wpT, bp, x, hbuf, C, C);
  k_ln1<<<dim3(MTOT), blk, 0, stream>>>(hbuf, ng, nb, hln);
  k_gemm<1><<<dim3(HID / 128, MTOT / 128), blk, 0, stream>>>(hln, w1T, b1, nullptr, y1, HID, C);
  k_gemm<2><<<dim3(C / 128, MTOT / 128), blk, 0, stream>>>(y1, w2T, b2, hbuf, (float*)d_out, C, HID);
}

// Round 7
// 551.314 us; speedup vs baseline: 1.3888x; 1.0326x over previous
//
#include <hip/hip_runtime.h>
#include <hip/hip_bf16.h>

#define DEV __device__ __forceinline__

typedef __attribute__((ext_vector_type(8))) short short8;
typedef __attribute__((ext_vector_type(4))) short short4v;
typedef __attribute__((ext_vector_type(4))) float f32x4;
typedef __attribute__((ext_vector_type(2))) int int2v;

constexpr int Bb   = 4;
constexpr int SEQ  = 2048;
constexpr int C    = 1024;
constexpr int HID  = 4096;
constexpr int NH   = 16;
constexpr int HD   = 64;
constexpr int MTOT = Bb * SEQ;   // 8192 tokens

DEV unsigned bfbits(float f) {
  unsigned x = __float_as_uint(f);
  return (x + 0x7fffu + ((x >> 16) & 1u)) >> 16;   // RNE to bf16, low 16 bits
}

DEV short f2bf(float f) { return (short)bfbits(f); }

// fast bf16 pair pack: +0x8000 (round-half-up, inputs positive finite) + byte perm
DEV unsigned packrn(float a, float b) {
  unsigned ua = __float_as_uint(a) + 0x8000u;
  unsigned ub = __float_as_uint(b) + 0x8000u;
  return __builtin_amdgcn_perm(ub, ua, 0x07060302u);
}

// raw v_exp_f32 (2^x), no OCML denorm guard (flush-to-zero fine for softmax)
DEV float fexp2(float x) {
#if __has_builtin(__builtin_amdgcn_exp2f)
  return __builtin_amdgcn_exp2f(x);
#else
  float r;
  asm("v_exp_f32 %0, %1" : "=v"(r) : "v"(x));
  return r;
#endif
}

DEV void gload16(const void* g, void* l) {
  __builtin_amdgcn_global_load_lds((const __attribute__((address_space(1))) void*)g,
                                   (__attribute__((address_space(3))) void*)l, 16, 0, 0);
}

// 16x16x16 bf16 MFMA (A/B = 2 VGPRs = 4 bf16)
DEV f32x4 mfma16(short4v a, short4v b, f32x4 c) {
#if __has_builtin(__builtin_amdgcn_mfma_f32_16x16x16bf16_1k)
  return __builtin_amdgcn_mfma_f32_16x16x16bf16_1k(a, b, c, 0, 0, 0);
#else
  asm volatile("v_mfma_f32_16x16x16_bf16 %0, %1, %2, %0" : "+v"(c) : "v"(a), "v"(b));
  return c;
#endif
}

// ---------------- weight transpose: fp32 [R][Cc] -> bf16 [Cc][R] ----------------
DEV void transpose_body(const float* __restrict__ src, short* __restrict__ dst,
                        int R, int Cc) {
  __shared__ float t[32][33];
  int tx = threadIdx.x & 31, ty = threadIdx.x >> 5;   // 32 x 8
  int c0 = blockIdx.x * 32, r0 = blockIdx.y * 32;
  #pragma unroll
  for (int i = 0; i < 4; i++)
    t[ty + i * 8][tx] = src[(size_t)(r0 + ty + i * 8) * Cc + c0 + tx];
  __syncthreads();
  #pragma unroll
  for (int i = 0; i < 4; i++)
    dst[(size_t)(c0 + ty + i * 8) * R + r0 + tx] = f2bf(t[tx][ty + i * 8]);
}

__global__ void k_transpose_w(const float* __restrict__ src, short* __restrict__ dst,
                              int R, int Cc) {
  transpose_body(src, dst, R, Cc);
}

// 4 square CxC transposes in one launch (z selects)
__global__ void k_transpose_w4(const float* __restrict__ s0, const float* __restrict__ s1,
                               const float* __restrict__ s2, const float* __restrict__ s3,
                               short* __restrict__ d0, short* __restrict__ d1,
                               short* __restrict__ d2, short* __restrict__ d3) {
  const float* s = blockIdx.z == 0 ? s0 : blockIdx.z == 1 ? s1 : blockIdx.z == 2 ? s2 : s3;
  short*       d = blockIdx.z == 0 ? d0 : blockIdx.z == 1 ? d1 : blockIdx.z == 2 ? d2 : d3;
  transpose_body(s, d, C, C);
}

// ---------------- V transpose: bf16 [tok][C] -> per-(b,h) [HD][SEQ] ----------------
__global__ void k_transpose_v(const short* __restrict__ V, short* __restrict__ Vt) {
  __shared__ short t[32][33];
  int tx = threadIdx.x & 31, ty = threadIdx.x >> 5;
  int plane = blockIdx.z;                 // b*16 + h
  int b = plane >> 4, h = plane & 15;
  int n0 = blockIdx.x * 32, d0 = blockIdx.y * 32;
  #pragma unroll
  for (int i = 0; i < 4; i++)
    t[ty + i * 8][tx] = V[(size_t)(b * SEQ + n0 + ty + i * 8) * C + h * HD + d0 + tx];
  __syncthreads();
  #pragma unroll
  for (int i = 0; i < 4; i++)
    Vt[((size_t)plane * HD + d0 + ty + i * 8) * SEQ + n0 + tx] = t[tx][ty + i * 8];
}

// ---------------- fused LN for q-input (x) and kv-input (x+pos) ----------------
__global__ void k_ln_qkv(const float* __restrict__ x, const float* __restrict__ pos,
                         const float* __restrict__ nqg, const float* __restrict__ nqb,
                         const float* __restrict__ nkg, const float* __restrict__ nkb,
                         const float* __restrict__ nvg, const float* __restrict__ nvb,
                         short* __restrict__ xq, short* __restrict__ xk,
                         short* __restrict__ xv) {
  int row = blockIdx.x, tid = threadIdx.x;
  int n = row & (SEQ - 1);
  float a4[4], p4[4];
  float s1 = 0, s2 = 0, t1 = 0, t2 = 0;
  #pragma unroll
  for (int i = 0; i < 4; i++) {
    int c = tid + i * 256;
    float a = x[(size_t)row * C + c];
    float p = pos[(size_t)n * C + c] + a;
    a4[i] = a; p4[i] = p;
    s1 += a; s2 += a * a; t1 += p; t2 += p * p;
  }
  #pragma unroll
  for (int off = 32; off; off >>= 1) {
    s1 += __shfl_xor(s1, off, 64);
    s2 += __shfl_xor(s2, off, 64);
    t1 += __shfl_xor(t1, off, 64);
    t2 += __shfl_xor(t2, off, 64);
  }
  __shared__ float red[4][4];
  int wave = tid >> 6, lane = tid & 63;
  if (lane == 0) { red[wave][0] = s1; red[wave][1] = s2; red[wave][2] = t1; red[wave][3] = t2; }
  __syncthreads();
  s1 = red[0][0] + red[1][0] + red[2][0] + red[3][0];
  s2 = red[0][1] + red[1][1] + red[2][1] + red[3][1];
  t1 = red[0][2] + red[1][2] + red[2][2] + red[3][2];
  t2 = red[0][3] + red[1][3] + red[2][3] + red[3][3];
  float mq = s1 * (1.f / C), mk = t1 * (1.f / C);
  float rq = rsqrtf(s2 * (1.f / C) - mq * mq + 1e-5f);
  float rk = rsqrtf(t2 * (1.f / C) - mk * mk + 1e-5f);
  #pragma unroll
  for (int i = 0; i < 4; i++) {
    int c = tid + i * 256;
    float nq_ = (a4[i] - mq) * rq;
    float nk_ = (p4[i] - mk) * rk;
    xq[(size_t)row * C + c] = f2bf(nq_ * nqg[c] + nqb[c]);
    xk[(size_t)row * C + c] = f2bf(nk_ * nkg[c] + nkb[c]);
    xv[(size_t)row * C + c] = f2bf(nk_ * nvg[c] + nvb[c]);
  }
}

// ---------------- plain LN (h -> bf16) ----------------
__global__ void k_ln1(const float* __restrict__ h, const float* __restrict__ g,
                      const float* __restrict__ bta, short* __restrict__ out) {
  int row = blockIdx.x, tid = threadIdx.x;
  float a4[4];
  float s1 = 0, s2 = 0;
  #pragma unroll
  for (int i = 0; i < 4; i++) {
    int c = tid + i * 256;
    float a = h[(size_t)row * C + c];
    a4[i] = a; s1 += a; s2 += a * a;
  }
  #pragma unroll
  for (int off = 32; off; off >>= 1) {
    s1 += __shfl_xor(s1, off, 64);
    s2 += __shfl_xor(s2, off, 64);
  }
  __shared__ float red[4][2];
  int wave = tid >> 6, lane = tid & 63;
  if (lane == 0) { red[wave][0] = s1; red[wave][1] = s2; }
  __syncthreads();
  s1 = red[0][0] + red[1][0] + red[2][0] + red[3][0];
  s2 = red[0][1] + red[1][1] + red[2][1] + red[3][1];
  float m = s1 * (1.f / C);
  float r = rsqrtf(s2 * (1.f / C) - m * m + 1e-5f);
  #pragma unroll
  for (int i = 0; i < 4; i++) {
    int c = tid + i * 256;
    out[(size_t)row * C + c] = f2bf((a4[i] - m) * r * g[c] + bta[c]);
  }
}

// ---------------- GEMM core: double-buffered global_load_lds, 1 barrier/iter ----------
// sA/sB are 2x(128x32) shorts. Prefetch for iter i+1 issued right after barrier i,
// drained at barrier i+1 (a full MFMA block of cover). DMA LDS layout lane-contiguous.
template <typename EPI>
DEV void gemm_body(const short* __restrict__ A, const short* __restrict__ Bt,
                   int Kk, short* sA, short* sB, EPI&& epi) {
  const int tid = threadIdx.x;
  const int wave = tid >> 6, lane = tid & 63, quad = lane >> 4, l15 = lane & 15;
  const int wm = (wave >> 1) * 64, wn = (wave & 1) * 64;
  constexpr int BO = 128 * 32;   // shorts per buffer

  const int r0 = tid >> 2, s0 = (tid & 3) * 8;
  const short* gA0 = A + (size_t)r0 * Kk + s0;
  const short* gA1 = A + (size_t)(r0 + 64) * Kk + s0;
  const short* gB0 = Bt + (size_t)r0 * Kk + s0;
  const short* gB1 = Bt + (size_t)(r0 + 64) * Kk + s0;
  short* lA0 = &sA[tid * 8];
  short* lA1 = &sA[(tid + 256) * 8];
  short* lB0 = &sB[tid * 8];
  short* lB1 = &sB[(tid + 256) * 8];

  const f32x4 fzero = {0.f, 0.f, 0.f, 0.f};
  f32x4 acc[4][4];
  #pragma unroll
  for (int mi = 0; mi < 4; mi++)
    #pragma unroll
    for (int ni = 0; ni < 4; ni++) acc[mi][ni] = fzero;

  // prologue: stage k0=0 into buf 0
  gload16(gA0, lA0);
  gload16(gA1, lA1);
  gload16(gB0, lB0);
  gload16(gB1, lB1);

  for (int k0 = 0; k0 < Kk; k0 += 32) {
    const int buf = (k0 >> 5) & 1;
    __syncthreads();   // per-wave vmcnt(0) drain + barrier: staging for `buf` complete,
                       // and all waves done reading buf^1 (safe to overwrite)
    if (k0 + 32 < Kk) {
      const int bo = (buf ^ 1) * BO;
      gload16(gA0 + k0 + 32, lA0 + bo);
      gload16(gA1 + k0 + 32, lA1 + bo);
      gload16(gB0 + k0 + 32, lB0 + bo);
      gload16(gB1 + k0 + 32, lB1 + bo);
    }
    const int bo = buf * BO;
    short8 av[4], bv[4];
    #pragma unroll
    for (int mi = 0; mi < 4; mi++)
      av[mi] = *(const short8*)&sA[bo + (wm + mi * 16 + l15) * 32 + quad * 8];
    #pragma unroll
    for (int ni = 0; ni < 4; ni++)
      bv[ni] = *(const short8*)&sB[bo + (wn + ni * 16 + l15) * 32 + quad * 8];
    #pragma unroll
    for (int mi = 0; mi < 4; mi++)
      #pragma unroll
      for (int ni = 0; ni < 4; ni++)
        acc[mi][ni] = __builtin_amdgcn_mfma_f32_16x16x32_bf16(av[mi], bv[ni], acc[mi][ni], 0, 0, 0);
  }
  epi(acc, wm, wn, quad, l15);
}

// Grid convention: blockIdx.x = M-block, blockIdx.y = N-block. A-tile sharers' linear
// ids differ by gridDim.x (multiple of 8) -> same XCD -> A fetched once per XCD L2.
// MODE 0: +bias -> bf16;  MODE 1: +bias, LeakyReLU(0.1) -> bf16;  MODE 2: +bias+resid -> fp32
template <int MODE>
__global__ __launch_bounds__(256, 2)
void k_gemm(const short* __restrict__ A, const short* __restrict__ Bt,
            const float* __restrict__ bias, const float* __restrict__ resid,
            void* __restrict__ outp, int Nn, int Kk) {
  __shared__ short sA[2 * 128 * 32];
  __shared__ short sB[2 * 128 * 32];
  const int m0 = blockIdx.x * 128, n0 = blockIdx.y * 128;
  gemm_body(A + (size_t)m0 * Kk, Bt + (size_t)n0 * Kk, Kk, sA, sB,
    [&](f32x4 (&acc)[4][4], int wm, int wn, int quad, int l15) {
      float bb[4];
      #pragma unroll
      for (int ni = 0; ni < 4; ni++) bb[ni] = bias[n0 + wn + ni * 16 + l15];
      #pragma unroll
      for (int mi = 0; mi < 4; mi++) {
        #pragma unroll
        for (int ni = 0; ni < 4; ni++) {
          #pragma unroll
          for (int r = 0; r < 4; r++) {
            int row = m0 + wm + mi * 16 + quad * 4 + r;   // C/D: row=quad*4+reg
            int col = n0 + wn + ni * 16 + l15;            //      col=lane&15
            float v = acc[mi][ni][r] + bb[ni];
            if constexpr (MODE == 1) v = v >= 0.f ? v : 0.1f * v;
            if constexpr (MODE == 2)
              ((float*)outp)[(size_t)row * Nn + col] = resid[(size_t)row * Nn + col] + v;
            else
              ((short*)outp)[(size_t)row * Nn + col] = f2bf(v);
          }
        }
      }
    });
}

// fused QKV projection: z selects {xq->Qm (scaled), xk->Km, xv->Vm}
__global__ __launch_bounds__(256, 2)
void k_gemm_qkv(const short* __restrict__ xq, const short* __restrict__ xk,
                const short* __restrict__ xv,
                const short* __restrict__ wqT, const short* __restrict__ wkT,
                const short* __restrict__ wvT,
                const float* __restrict__ bq, const float* __restrict__ bk,
                const float* __restrict__ bv,
                short* __restrict__ Qm, short* __restrict__ Km, short* __restrict__ Vm) {
  __shared__ short sA[2 * 128 * 32];
  __shared__ short sB[2 * 128 * 32];
  const int z = blockIdx.z;
  const short* A    = z == 0 ? xq : z == 1 ? xk : xv;
  const short* Bt   = z == 0 ? wqT : z == 1 ? wkT : wvT;
  const float* bias = z == 0 ? bq : z == 1 ? bk : bv;
  short* outp       = z == 0 ? Qm : z == 1 ? Km : Vm;
  const float scale = z == 0 ? 0.1803368801111244f : 1.0f;   // 0.125 * log2(e) on Q
  const int m0 = blockIdx.x * 128, n0 = blockIdx.y * 128;
  gemm_body(A + (size_t)m0 * C, Bt + (size_t)n0 * C, C, sA, sB,
    [&](f32x4 (&acc)[4][4], int wm, int wn, int quad, int l15) {
      float bb[4];
      #pragma unroll
      for (int ni = 0; ni < 4; ni++) bb[ni] = bias[n0 + wn + ni * 16 + l15];
      #pragma unroll
      for (int mi = 0; mi < 4; mi++)
        #pragma unroll
        for (int ni = 0; ni < 4; ni++)
          #pragma unroll
          for (int r = 0; r < 4; r++) {
            int row = m0 + wm + mi * 16 + quad * 4 + r;
            int col = n0 + wn + ni * 16 + l15;
            outp[(size_t)row * C + col] = f2bf((acc[mi][ni][r] + bb[ni]) * scale);
          }
    });
}

// ---------------- flash attention, S^T formulation, async double-buffered K/V ----------------
// S^T C-layout (key=quad*4+r, q=l15) IS the 16x16x16 A-operand layout (m=l15, k=quad*4+j),
// so PV runs on mfma_16x16x16 with the packed exp2 results as A directly. Row-sums via
// MFMA with a ones-B (lands in C-layout, same indexing as O).
__global__ __launch_bounds__(256, 4)
void k_attn(const short* __restrict__ Q, const short* __restrict__ K,
            const short* __restrict__ Vt, short* __restrict__ O) {
  __shared__ __align__(16) short sK[2][64 * 64];
  __shared__ __align__(16) short sV[2][64 * 64];   // Vt tile: [d][key]
  const int tid = threadIdx.x;
  const int bh = blockIdx.x;                        // bh fastest -> XCD-pinned K/V reuse
  const int b = bh >> 4, h = bh & 15;
  const int q0 = blockIdx.y * 128;
  const int wave = tid >> 6, lane = tid & 63, quad = lane >> 4, l15 = lane & 15;
  const int wm = wave * 32;        // 32 q-rows per wave
  const size_t tokBase = (size_t)b * SEQ;

  // Q fragments in registers (B-operand of QK^T): [qi][d-half]
  short8 qf[2][2];
  #pragma unroll
  for (int qi = 0; qi < 2; qi++)
    #pragma unroll
    for (int hf = 0; hf < 2; hf++)
      qf[qi][hf] = *(const short8*)(Q + (tokBase + q0 + wm + qi * 16 + l15) * C
                                    + h * HD + hf * 32 + quad * 8);

  // staging: 2 slots/thread/array; store global seg (slot&7)^(row&7) at phys seg slot&7
  const int r0 = tid >> 3,        c0s = ((tid & 7) ^ (r0 & 7)) * 8;
  const int r1 = (tid + 256) >> 3, c1s = ((tid & 7) ^ (r1 & 7)) * 8;
  const short* gK0 = K + (tokBase + r0) * C + h * HD + c0s;
  const short* gK1 = K + (tokBase + r1) * C + h * HD + c1s;
  const short* gV0 = Vt + ((size_t)bh * HD + r0) * SEQ + c0s;
  const short* gV1 = Vt + ((size_t)bh * HD + r1) * SEQ + c1s;
  short* lK0 = &sK[0][tid * 8];
  short* lK1 = &sK[0][(tid + 256) * 8];
  short* lV0 = &sV[0][tid * 8];
  short* lV1 = &sV[0][(tid + 256) * 8];
  constexpr int BUFO = 64 * 64;   // shorts per buffer

#define STAGE(bufsel, kb) {                                   \
    int kk = (kb) * 64, bo = (bufsel) * BUFO;                 \
    gload16(gK0 + (size_t)kk * C, lK0 + bo);                  \
    gload16(gK1 + (size_t)kk * C, lK1 + bo);                  \
    gload16(gV0 + kk,             lV0 + bo);                  \
    gload16(gV1 + kk,             lV1 + bo); }

  const f32x4 fzero = {0.f, 0.f, 0.f, 0.f};
  const short4v onesv = {0x3F80, 0x3F80, 0x3F80, 0x3F80};   // bf16 1.0 x4
  f32x4 o[2][4];
  f32x4 oSum[2] = {fzero, fzero};
  #pragma unroll
  for (int qi = 0; qi < 2; qi++)
    #pragma unroll
    for (int di = 0; di < 4; di++) o[qi][di] = fzero;

  const int sw = l15 & 7;                    // seg swizzle key

  STAGE(0, 0)

  for (int kb = 0; kb < SEQ / 64; kb++) {
    const int buf = kb & 1;
    __syncthreads();                         // drains prefetch vmcnt; guards buf reuse
    if (kb + 1 < SEQ / 64) STAGE(buf ^ 1, kb + 1)

    // S^T tiles: D[key][q], key=quad*4+r (within ki*16), q=l15; exp2 + pack immediately.
    // pk[ki][qi][0..1] = packed P row fragment == x16 A-operand.
    unsigned pk[4][2][2];
    #pragma unroll
    for (int ki = 0; ki < 4; ki++) {
      const int krow = (ki * 16 + l15) * 64;
      short8 a0 = *(const short8*)&sK[buf][krow + ((0 + quad) ^ sw) * 8];
      short8 a1 = *(const short8*)&sK[buf][krow + ((4 + quad) ^ sw) * 8];
      #pragma unroll
      for (int qi = 0; qi < 2; qi++) {
        f32x4 st = __builtin_amdgcn_mfma_f32_16x16x32_bf16(a0, qf[qi][0], fzero, 0, 0, 0);
        st = __builtin_amdgcn_mfma_f32_16x16x32_bf16(a1, qf[qi][1], st, 0, 0, 0);
        float p0 = fexp2(st[0]), p1 = fexp2(st[1]);
        float p2 = fexp2(st[2]), p3 = fexp2(st[3]);
        pk[ki][qi][0] = packrn(p0, p1);
        pk[ki][qi][1] = packrn(p2, p3);
      }
    }

    // PV + row-sum, all on 16x16x16 MFMA; V B-fragment = 4 consecutive keys (b64 read)
    #pragma unroll
    for (int ki = 0; ki < 4; ki++) {
      short4v bv[4];
      const int g = ((ki * 2 + (quad >> 1)) ^ sw) * 8 + (quad & 1) * 4;
      #pragma unroll
      for (int di = 0; di < 4; di++)
        bv[di] = *(const short4v*)&sV[buf][(di * 16 + l15) * 64 + g];
      #pragma unroll
      for (int qi = 0; qi < 2; qi++) {
        int2v t; t.x = (int)pk[ki][qi][0]; t.y = (int)pk[ki][qi][1];
        short4v aP = __builtin_bit_cast(short4v, t);
        oSum[qi] = mfma16(aP, onesv, oSum[qi]);
        #pragma unroll
        for (int di = 0; di < 4; di++)
          o[qi][di] = mfma16(aP, bv[di], o[qi][di]);
      }
    }
  }
#undef STAGE

  // oSum C-layout row=quad*4+r holds the softmax denom for that q — same indexing as o
  float linv[2][4];
  #pragma unroll
  for (int qi = 0; qi < 2; qi++)
    #pragma unroll
    for (int r = 0; r < 4; r++)
      linv[qi][r] = 1.0f / oSum[qi][r];

  #pragma unroll
  for (int qi = 0; qi < 2; qi++)
    #pragma unroll
    for (int di = 0; di < 4; di++)
      #pragma unroll
      for (int r = 0; r < 4; r++) {
        int row = q0 + wm + qi * 16 + quad * 4 + r;
        int col = h * HD + di * 16 + l15;
        O[(tokBase + row) * C + col] = f2bf(o[qi][di][r] * linv[qi][r]);
      }
}

extern "C" void kernel_launch(void* const* d_in, const int* in_sizes, int n_in,
                              void* d_out, int out_size, void* d_ws, size_t ws_size,
                              hipStream_t stream) {
  const float* x   = (const float*)d_in[0];
  const float* pos = (const float*)d_in[1];
  const float* nqg = (const float*)d_in[2];
  const float* nqb = (const float*)d_in[3];
  const float* nkg = (const float*)d_in[4];
  const float* nkb = (const float*)d_in[5];
  const float* nvg = (const float*)d_in[6];
  const float* nvb = (const float*)d_in[7];
  const float* ng  = (const float*)d_in[8];
  const float* nb  = (const float*)d_in[9];
  const float* wq  = (const float*)d_in[10];
  const float* bq  = (const float*)d_in[11];
  const float* wk  = (const float*)d_in[12];
  const float* bk  = (const float*)d_in[13];
  const float* wv  = (const float*)d_in[14];
  const float* bv  = (const float*)d_in[15];
  const float* wp  = (const float*)d_in[16];
  const float* bp  = (const float*)d_in[17];
  const float* w1  = (const float*)d_in[18];
  const float* b1  = (const float*)d_in[19];
  const float* w2  = (const float*)d_in[20];
  const float* b2  = (const float*)d_in[21];

  char* ws = (char*)d_ws;
  const size_t MB = 1u << 20;
  short* wqT  = (short*)(ws + 0 * MB);
  short* wkT  = (short*)(ws + 2 * MB);
  short* wvT  = (short*)(ws + 4 * MB);
  short* wpT  = (short*)(ws + 6 * MB);
  short* w1T  = (short*)(ws + 8 * MB);     // [HID][C]
  short* w2T  = (short*)(ws + 16 * MB);    // [C][HID]
  short* xq   = (short*)(ws + 24 * MB);
  short* xk   = (short*)(ws + 40 * MB);
  short* xv   = (short*)(ws + 56 * MB);
  short* Qm   = (short*)(ws + 72 * MB);
  short* Km   = (short*)(ws + 88 * MB);
  short* Vm   = (short*)(ws + 104 * MB);
  short* Vt   = (short*)(ws + 120 * MB);
  short* y1   = (short*)(ws + 72 * MB);    // overlays Q/K/V/Vt (dead after attn)
  short* Ob   = xk;                         // overlays xk (dead after K-proj)
  short* hln  = xq;                         // overlays xq (dead after Q-proj)
  float* hbuf = (float*)(ws + 136 * MB);
  (void)ws_size; (void)in_sizes; (void)n_in; (void)out_size;

  dim3 blk(256);
  k_transpose_w4<<<dim3(32, 32, 4), blk, 0, stream>>>(wq, wk, wv, wp, wqT, wkT, wvT, wpT);
  k_transpose_w<<<dim3(128, 32), blk, 0, stream>>>(w1, w1T, C, HID);
  k_transpose_w<<<dim3(32, 128), blk, 0, stream>>>(w2, w2T, HID, C);
  k_ln_qkv<<<dim3(MTOT), blk, 0, stream>>>(x, pos, nqg, nqb, nkg, nkb, nvg, nvb, xq, xk, xv);
  k_gemm_qkv<<<dim3(MTOT / 128, C / 128, 3), blk, 0, stream>>>(xq, xk, xv, wqT, wkT, wvT,
                                                               bq, bk, bv, Qm, Km, Vm);
  k_transpose_v<<<dim3(SEQ / 32, HD / 32, Bb * NH), blk, 0, stream>>>(Vm, Vt);
  k_attn<<<dim3(Bb * NH, SEQ / 128), blk, 0, stream>>>(Qm, Km, Vt, Ob);
  k_gemm<2><<<dim3(MTOT / 128, C / 128), blk, 0, stream>>>(Ob, wpT, bp, x, hbuf, C, C);
  k_ln1<<<dim3(MTOT), blk, 0, stream>>>(hbuf, ng, nb, hln);
  k_gemm<1><<<dim3(MTOT / 128, HID / 128), blk, 0, stream>>>(hln, w1T, b1, nullptr, y1, HID, C);
  k_gemm<2><<<dim3(MTOT / 128, C / 128), blk, 0, stream>>>(y1, w2T, b2, hbuf, (float*)d_out, C, HID);
}

// Round 8
// 550.900 us; speedup vs baseline: 1.3899x; 1.0008x over previous
//
#include <hip/hip_runtime.h>
#include <hip/hip_bf16.h>

#define DEV __device__ __forceinline__

typedef __attribute__((ext_vector_type(8))) short short8;
typedef __attribute__((ext_vector_type(4))) short short4v;
typedef __attribute__((ext_vector_type(4))) float f32x4;
typedef __attribute__((ext_vector_type(2))) int int2v;

constexpr int Bb   = 4;
constexpr int SEQ  = 2048;
constexpr int C    = 1024;
constexpr int HID  = 4096;
constexpr int NH   = 16;
constexpr int HD   = 64;
constexpr int MTOT = Bb * SEQ;   // 8192 tokens

DEV unsigned bfbits(float f) {
  unsigned x = __float_as_uint(f);
  return (x + 0x7fffu + ((x >> 16) & 1u)) >> 16;   // RNE to bf16, low 16 bits
}

DEV short f2bf(float f) { return (short)bfbits(f); }

// fast bf16 pair pack: +0x8000 (round-half-up, inputs positive finite) + byte perm
DEV unsigned packrn(float a, float b) {
  unsigned ua = __float_as_uint(a) + 0x8000u;
  unsigned ub = __float_as_uint(b) + 0x8000u;
  return __builtin_amdgcn_perm(ub, ua, 0x07060302u);
}

// raw v_exp_f32 (2^x), no OCML denorm guard (flush-to-zero fine for softmax)
DEV float fexp2(float x) {
#if __has_builtin(__builtin_amdgcn_exp2f)
  return __builtin_amdgcn_exp2f(x);
#else
  float r;
  asm("v_exp_f32 %0, %1" : "=v"(r) : "v"(x));
  return r;
#endif
}

DEV void gload16(const void* g, void* l) {
  __builtin_amdgcn_global_load_lds((const __attribute__((address_space(1))) void*)g,
                                   (__attribute__((address_space(3))) void*)l, 16, 0, 0);
}

// 16x16x16 bf16 MFMA (A/B = 2 VGPRs = 4 bf16)
DEV f32x4 mfma16(short4v a, short4v b, f32x4 c) {
#if __has_builtin(__builtin_amdgcn_mfma_f32_16x16x16bf16_1k)
  return __builtin_amdgcn_mfma_f32_16x16x16bf16_1k(a, b, c, 0, 0, 0);
#else
  asm volatile("v_mfma_f32_16x16x16_bf16 %0, %1, %2, %0" : "+v"(c) : "v"(a), "v"(b));
  return c;
#endif
}

// ---------------- weight transpose: fp32 [R][Cc] -> bf16 [Cc][R] ----------------
DEV void transpose_body(const float* __restrict__ src, short* __restrict__ dst,
                        int R, int Cc) {
  __shared__ float t[32][33];
  int tx = threadIdx.x & 31, ty = threadIdx.x >> 5;   // 32 x 8
  int c0 = blockIdx.x * 32, r0 = blockIdx.y * 32;
  #pragma unroll
  for (int i = 0; i < 4; i++)
    t[ty + i * 8][tx] = src[(size_t)(r0 + ty + i * 8) * Cc + c0 + tx];
  __syncthreads();
  #pragma unroll
  for (int i = 0; i < 4; i++)
    dst[(size_t)(c0 + ty + i * 8) * R + r0 + tx] = f2bf(t[tx][ty + i * 8]);
}

__global__ void k_transpose_w(const float* __restrict__ src, short* __restrict__ dst,
                              int R, int Cc) {
  transpose_body(src, dst, R, Cc);
}

// 4 square CxC transposes in one launch (z selects)
__global__ void k_transpose_w4(const float* __restrict__ s0, const float* __restrict__ s1,
                               const float* __restrict__ s2, const float* __restrict__ s3,
                               short* __restrict__ d0, short* __restrict__ d1,
                               short* __restrict__ d2, short* __restrict__ d3) {
  const float* s = blockIdx.z == 0 ? s0 : blockIdx.z == 1 ? s1 : blockIdx.z == 2 ? s2 : s3;
  short*       d = blockIdx.z == 0 ? d0 : blockIdx.z == 1 ? d1 : blockIdx.z == 2 ? d2 : d3;
  transpose_body(s, d, C, C);
}

// ---------------- V transpose: bf16 [tok][C] -> per-(b,h) [HD][SEQ] ----------------
__global__ void k_transpose_v(const short* __restrict__ V, short* __restrict__ Vt) {
  __shared__ short t[32][33];
  int tx = threadIdx.x & 31, ty = threadIdx.x >> 5;
  int plane = blockIdx.z;                 // b*16 + h
  int b = plane >> 4, h = plane & 15;
  int n0 = blockIdx.x * 32, d0 = blockIdx.y * 32;
  #pragma unroll
  for (int i = 0; i < 4; i++)
    t[ty + i * 8][tx] = V[(size_t)(b * SEQ + n0 + ty + i * 8) * C + h * HD + d0 + tx];
  __syncthreads();
  #pragma unroll
  for (int i = 0; i < 4; i++)
    Vt[((size_t)plane * HD + d0 + ty + i * 8) * SEQ + n0 + tx] = t[tx][ty + i * 8];
}

// ---------------- fused LN for q-input (x) and kv-input (x+pos) ----------------
__global__ void k_ln_qkv(const float* __restrict__ x, const float* __restrict__ pos,
                         const float* __restrict__ nqg, const float* __restrict__ nqb,
                         const float* __restrict__ nkg, const float* __restrict__ nkb,
                         const float* __restrict__ nvg, const float* __restrict__ nvb,
                         short* __restrict__ xq, short* __restrict__ xk,
                         short* __restrict__ xv) {
  int row = blockIdx.x, tid = threadIdx.x;
  int n = row & (SEQ - 1);
  float a4[4], p4[4];
  float s1 = 0, s2 = 0, t1 = 0, t2 = 0;
  #pragma unroll
  for (int i = 0; i < 4; i++) {
    int c = tid + i * 256;
    float a = x[(size_t)row * C + c];
    float p = pos[(size_t)n * C + c] + a;
    a4[i] = a; p4[i] = p;
    s1 += a; s2 += a * a; t1 += p; t2 += p * p;
  }
  #pragma unroll
  for (int off = 32; off; off >>= 1) {
    s1 += __shfl_xor(s1, off, 64);
    s2 += __shfl_xor(s2, off, 64);
    t1 += __shfl_xor(t1, off, 64);
    t2 += __shfl_xor(t2, off, 64);
  }
  __shared__ float red[4][4];
  int wave = tid >> 6, lane = tid & 63;
  if (lane == 0) { red[wave][0] = s1; red[wave][1] = s2; red[wave][2] = t1; red[wave][3] = t2; }
  __syncthreads();
  s1 = red[0][0] + red[1][0] + red[2][0] + red[3][0];
  s2 = red[0][1] + red[1][1] + red[2][1] + red[3][1];
  t1 = red[0][2] + red[1][2] + red[2][2] + red[3][2];
  t2 = red[0][3] + red[1][3] + red[2][3] + red[3][3];
  float mq = s1 * (1.f / C), mk = t1 * (1.f / C);
  float rq = rsqrtf(s2 * (1.f / C) - mq * mq + 1e-5f);
  float rk = rsqrtf(t2 * (1.f / C) - mk * mk + 1e-5f);
  #pragma unroll
  for (int i = 0; i < 4; i++) {
    int c = tid + i * 256;
    float nq_ = (a4[i] - mq) * rq;
    float nk_ = (p4[i] - mk) * rk;
    xq[(size_t)row * C + c] = f2bf(nq_ * nqg[c] + nqb[c]);
    xk[(size_t)row * C + c] = f2bf(nk_ * nkg[c] + nkb[c]);
    xv[(size_t)row * C + c] = f2bf(nk_ * nvg[c] + nvb[c]);
  }
}

// ---------------- plain LN (h -> bf16) ----------------
__global__ void k_ln1(const float* __restrict__ h, const float* __restrict__ g,
                      const float* __restrict__ bta, short* __restrict__ out) {
  int row = blockIdx.x, tid = threadIdx.x;
  float a4[4];
  float s1 = 0, s2 = 0;
  #pragma unroll
  for (int i = 0; i < 4; i++) {
    int c = tid + i * 256;
    float a = h[(size_t)row * C + c];
    a4[i] = a; s1 += a; s2 += a * a;
  }
  #pragma unroll
  for (int off = 32; off; off >>= 1) {
    s1 += __shfl_xor(s1, off, 64);
    s2 += __shfl_xor(s2, off, 64);
  }
  __shared__ float red[4][2];
  int wave = tid >> 6, lane = tid & 63;
  if (lane == 0) { red[wave][0] = s1; red[wave][1] = s2; }
  __syncthreads();
  s1 = red[0][0] + red[1][0] + red[2][0] + red[3][0];
  s2 = red[0][1] + red[1][1] + red[2][1] + red[3][1];
  float m = s1 * (1.f / C);
  float r = rsqrtf(s2 * (1.f / C) - m * m + 1e-5f);
  #pragma unroll
  for (int i = 0; i < 4; i++) {
    int c = tid + i * 256;
    out[(size_t)row * C + c] = f2bf((a4[i] - m) * r * g[c] + bta[c]);
  }
}

// ---------------- GEMM core: double-buffered global_load_lds, 1 barrier/iter ----------
template <typename EPI>
DEV void gemm_body(const short* __restrict__ A, const short* __restrict__ Bt,
                   int Kk, short* sA, short* sB, EPI&& epi) {
  const int tid = threadIdx.x;
  const int wave = tid >> 6, lane = tid & 63, quad = lane >> 4, l15 = lane & 15;
  const int wm = (wave >> 1) * 64, wn = (wave & 1) * 64;
  constexpr int BO = 128 * 32;   // shorts per buffer

  const int r0 = tid >> 2, s0 = (tid & 3) * 8;
  const short* gA0 = A + (size_t)r0 * Kk + s0;
  const short* gA1 = A + (size_t)(r0 + 64) * Kk + s0;
  const short* gB0 = Bt + (size_t)r0 * Kk + s0;
  const short* gB1 = Bt + (size_t)(r0 + 64) * Kk + s0;
  short* lA0 = &sA[tid * 8];
  short* lA1 = &sA[(tid + 256) * 8];
  short* lB0 = &sB[tid * 8];
  short* lB1 = &sB[(tid + 256) * 8];

  const f32x4 fzero = {0.f, 0.f, 0.f, 0.f};
  f32x4 acc[4][4];
  #pragma unroll
  for (int mi = 0; mi < 4; mi++)
    #pragma unroll
    for (int ni = 0; ni < 4; ni++) acc[mi][ni] = fzero;

  gload16(gA0, lA0);
  gload16(gA1, lA1);
  gload16(gB0, lB0);
  gload16(gB1, lB1);

  for (int k0 = 0; k0 < Kk; k0 += 32) {
    const int buf = (k0 >> 5) & 1;
    __syncthreads();
    if (k0 + 32 < Kk) {
      const int bo = (buf ^ 1) * BO;
      gload16(gA0 + k0 + 32, lA0 + bo);
      gload16(gA1 + k0 + 32, lA1 + bo);
      gload16(gB0 + k0 + 32, lB0 + bo);
      gload16(gB1 + k0 + 32, lB1 + bo);
    }
    const int bo = buf * BO;
    short8 av[4], bv[4];
    #pragma unroll
    for (int mi = 0; mi < 4; mi++)
      av[mi] = *(const short8*)&sA[bo + (wm + mi * 16 + l15) * 32 + quad * 8];
    #pragma unroll
    for (int ni = 0; ni < 4; ni++)
      bv[ni] = *(const short8*)&sB[bo + (wn + ni * 16 + l15) * 32 + quad * 8];
    #pragma unroll
    for (int mi = 0; mi < 4; mi++)
      #pragma unroll
      for (int ni = 0; ni < 4; ni++)
        acc[mi][ni] = __builtin_amdgcn_mfma_f32_16x16x32_bf16(av[mi], bv[ni], acc[mi][ni], 0, 0, 0);
  }
  epi(acc, wm, wn, quad, l15);
}

// 128x128-tile GEMM. Grid: x = M-blocks, y = N-blocks (A-sharers -> same XCD).
// MODE 0: +bias -> bf16;  MODE 1: +bias, LeakyReLU(0.1) -> bf16;  MODE 2: +bias+resid -> fp32
template <int MODE>
__global__ __launch_bounds__(256, 2)
void k_gemm(const short* __restrict__ A, const short* __restrict__ Bt,
            const float* __restrict__ bias, const float* __restrict__ resid,
            void* __restrict__ outp, int Nn, int Kk) {
  __shared__ short sA[2 * 128 * 32];
  __shared__ short sB[2 * 128 * 32];
  const int m0 = blockIdx.x * 128, n0 = blockIdx.y * 128;
  gemm_body(A + (size_t)m0 * Kk, Bt + (size_t)n0 * Kk, Kk, sA, sB,
    [&](f32x4 (&acc)[4][4], int wm, int wn, int quad, int l15) {
      float bb[4];
      #pragma unroll
      for (int ni = 0; ni < 4; ni++) bb[ni] = bias[n0 + wn + ni * 16 + l15];
      #pragma unroll
      for (int mi = 0; mi < 4; mi++) {
        #pragma unroll
        for (int ni = 0; ni < 4; ni++) {
          #pragma unroll
          for (int r = 0; r < 4; r++) {
            int row = m0 + wm + mi * 16 + quad * 4 + r;   // C/D: row=quad*4+reg
            int col = n0 + wn + ni * 16 + l15;            //      col=lane&15
            float v = acc[mi][ni][r] + bb[ni];
            if constexpr (MODE == 1) v = v >= 0.f ? v : 0.1f * v;
            if constexpr (MODE == 2)
              ((float*)outp)[(size_t)row * Nn + col] = resid[(size_t)row * Nn + col] + v;
            else
              ((short*)outp)[(size_t)row * Nn + col] = f2bf(v);
          }
        }
      }
    });
}

// 128Mx64N-tile GEMM for grid-starved shapes (wp, MLP2): 2x the blocks -> 4 blocks/CU.
// LDS 24 KB; acc 2x4 per wave (wave covers 32 rows x 64 cols).
template <int MODE>
__global__ __launch_bounds__(256, 4)
void k_gemm_n64(const short* __restrict__ A, const short* __restrict__ Bt,
                const float* __restrict__ bias, const float* __restrict__ resid,
                void* __restrict__ outp, int Nn, int Kk) {
  __shared__ short sA[2 * 128 * 32];
  __shared__ short sB[2 * 64 * 32];
  constexpr int BOA = 128 * 32, BOB = 64 * 32;
  const int tid = threadIdx.x;
  const int m0 = blockIdx.x * 128, n0 = blockIdx.y * 64;
  const int wave = tid >> 6, lane = tid & 63, quad = lane >> 4, l15 = lane & 15;
  const int wm = wave * 32;

  const int r0 = tid >> 2, s0 = (tid & 3) * 8;
  const short* gA0 = A + (size_t)(m0 + r0) * Kk + s0;
  const short* gA1 = A + (size_t)(m0 + r0 + 64) * Kk + s0;
  const short* gB0 = Bt + (size_t)(n0 + r0) * Kk + s0;
  short* lA0 = &sA[tid * 8];
  short* lA1 = &sA[(tid + 256) * 8];
  short* lB0 = &sB[tid * 8];

  const f32x4 fzero = {0.f, 0.f, 0.f, 0.f};
  f32x4 acc[2][4];
  #pragma unroll
  for (int mi = 0; mi < 2; mi++)
    #pragma unroll
    for (int ni = 0; ni < 4; ni++) acc[mi][ni] = fzero;

  gload16(gA0, lA0);
  gload16(gA1, lA1);
  gload16(gB0, lB0);

  for (int k0 = 0; k0 < Kk; k0 += 32) {
    const int buf = (k0 >> 5) & 1;
    __syncthreads();
    if (k0 + 32 < Kk) {
      gload16(gA0 + k0 + 32, lA0 + (buf ^ 1) * BOA);
      gload16(gA1 + k0 + 32, lA1 + (buf ^ 1) * BOA);
      gload16(gB0 + k0 + 32, lB0 + (buf ^ 1) * BOB);
    }
    const int boA = buf * BOA, boB = buf * BOB;
    short8 av[2], bv[4];
    #pragma unroll
    for (int mi = 0; mi < 2; mi++)
      av[mi] = *(const short8*)&sA[boA + (wm + mi * 16 + l15) * 32 + quad * 8];
    #pragma unroll
    for (int ni = 0; ni < 4; ni++)
      bv[ni] = *(const short8*)&sB[boB + (ni * 16 + l15) * 32 + quad * 8];
    #pragma unroll
    for (int mi = 0; mi < 2; mi++)
      #pragma unroll
      for (int ni = 0; ni < 4; ni++)
        acc[mi][ni] = __builtin_amdgcn_mfma_f32_16x16x32_bf16(av[mi], bv[ni], acc[mi][ni], 0, 0, 0);
  }

  float bb[4];
  #pragma unroll
  for (int ni = 0; ni < 4; ni++) bb[ni] = bias[n0 + ni * 16 + l15];
  #pragma unroll
  for (int mi = 0; mi < 2; mi++) {
    #pragma unroll
    for (int ni = 0; ni < 4; ni++) {
      #pragma unroll
      for (int r = 0; r < 4; r++) {
        int row = m0 + wm + mi * 16 + quad * 4 + r;
        int col = n0 + ni * 16 + l15;
        float v = acc[mi][ni][r] + bb[ni];
        if constexpr (MODE == 1) v = v >= 0.f ? v : 0.1f * v;
        if constexpr (MODE == 2)
          ((float*)outp)[(size_t)row * Nn + col] = resid[(size_t)row * Nn + col] + v;
        else
          ((short*)outp)[(size_t)row * Nn + col] = f2bf(v);
      }
    }
  }
}

// fused QKV projection: z selects {xq->Qm (scaled), xk->Km, xv->Vm}
__global__ __launch_bounds__(256, 2)
void k_gemm_qkv(const short* __restrict__ xq, const short* __restrict__ xk,
                const short* __restrict__ xv,
                const short* __restrict__ wqT, const short* __restrict__ wkT,
                const short* __restrict__ wvT,
                const float* __restrict__ bq, const float* __restrict__ bk,
                const float* __restrict__ bv,
                short* __restrict__ Qm, short* __restrict__ Km, short* __restrict__ Vm) {
  __shared__ short sA[2 * 128 * 32];
  __shared__ short sB[2 * 128 * 32];
  const int z = blockIdx.z;
  const short* A    = z == 0 ? xq : z == 1 ? xk : xv;
  const short* Bt   = z == 0 ? wqT : z == 1 ? wkT : wvT;
  const float* bias = z == 0 ? bq : z == 1 ? bk : bv;
  short* outp       = z == 0 ? Qm : z == 1 ? Km : Vm;
  const float scale = z == 0 ? 0.1803368801111244f : 1.0f;   // 0.125 * log2(e) on Q
  const int m0 = blockIdx.x * 128, n0 = blockIdx.y * 128;
  gemm_body(A + (size_t)m0 * C, Bt + (size_t)n0 * C, C, sA, sB,
    [&](f32x4 (&acc)[4][4], int wm, int wn, int quad, int l15) {
      float bb[4];
      #pragma unroll
      for (int ni = 0; ni < 4; ni++) bb[ni] = bias[n0 + wn + ni * 16 + l15];
      #pragma unroll
      for (int mi = 0; mi < 4; mi++)
        #pragma unroll
        for (int ni = 0; ni < 4; ni++)
          #pragma unroll
          for (int r = 0; r < 4; r++) {
            int row = m0 + wm + mi * 16 + quad * 4 + r;
            int col = n0 + wn + ni * 16 + l15;
            outp[(size_t)row * C + col] = f2bf((acc[mi][ni][r] + bb[ni]) * scale);
          }
    });
}

// ---------------- flash attention, S^T formulation, async double-buffered K/V ----------------
__global__ __launch_bounds__(256, 4)
void k_attn(const short* __restrict__ Q, const short* __restrict__ K,
            const short* __restrict__ Vt, short* __restrict__ O) {
  __shared__ __align__(16) short sK[2][64 * 64];
  __shared__ __align__(16) short sV[2][64 * 64];   // Vt tile: [d][key]
  const int tid = threadIdx.x;
  const int bh = blockIdx.x;                        // bh fastest -> XCD-pinned K/V reuse
  const int b = bh >> 4, h = bh & 15;
  const int q0 = blockIdx.y * 128;
  const int wave = tid >> 6, lane = tid & 63, quad = lane >> 4, l15 = lane & 15;
  const int wm = wave * 32;        // 32 q-rows per wave
  const size_t tokBase = (size_t)b * SEQ;

  // Q fragments in registers (B-operand of QK^T): [qi][d-half]
  short8 qf[2][2];
  #pragma unroll
  for (int qi = 0; qi < 2; qi++)
    #pragma unroll
    for (int hf = 0; hf < 2; hf++)
      qf[qi][hf] = *(const short8*)(Q + (tokBase + q0 + wm + qi * 16 + l15) * C
                                    + h * HD + hf * 32 + quad * 8);

  const int r0 = tid >> 3,        c0s = ((tid & 7) ^ (r0 & 7)) * 8;
  const int r1 = (tid + 256) >> 3, c1s = ((tid & 7) ^ (r1 & 7)) * 8;
  const short* gK0 = K + (tokBase + r0) * C + h * HD + c0s;
  const short* gK1 = K + (tokBase + r1) * C + h * HD + c1s;
  const short* gV0 = Vt + ((size_t)bh * HD + r0) * SEQ + c0s;
  const short* gV1 = Vt + ((size_t)bh * HD + r1) * SEQ + c1s;
  short* lK0 = &sK[0][tid * 8];
  short* lK1 = &sK[0][(tid + 256) * 8];
  short* lV0 = &sV[0][tid * 8];
  short* lV1 = &sV[0][(tid + 256) * 8];
  constexpr int BUFO = 64 * 64;   // shorts per buffer

#define STAGE(bufsel, kb) {                                   \
    int kk = (kb) * 64, bo = (bufsel) * BUFO;                 \
    gload16(gK0 + (size_t)kk * C, lK0 + bo);                  \
    gload16(gK1 + (size_t)kk * C, lK1 + bo);                  \
    gload16(gV0 + kk,             lV0 + bo);                  \
    gload16(gV1 + kk,             lV1 + bo); }

  const f32x4 fzero = {0.f, 0.f, 0.f, 0.f};
  const short4v onesv = {0x3F80, 0x3F80, 0x3F80, 0x3F80};   // bf16 1.0 x4
  f32x4 o[2][4];
  f32x4 oSum[2] = {fzero, fzero};
  #pragma unroll
  for (int qi = 0; qi < 2; qi++)
    #pragma unroll
    for (int di = 0; di < 4; di++) o[qi][di] = fzero;

  const int sw = l15 & 7;                    // seg swizzle key

  STAGE(0, 0)

  for (int kb = 0; kb < SEQ / 64; kb++) {
    const int buf = kb & 1;
    __syncthreads();
    if (kb + 1 < SEQ / 64) STAGE(buf ^ 1, kb + 1)

    unsigned pk[4][2][2];
    #pragma unroll
    for (int ki = 0; ki < 4; ki++) {
      const int krow = (ki * 16 + l15) * 64;
      short8 a0 = *(const short8*)&sK[buf][krow + ((0 + quad) ^ sw) * 8];
      short8 a1 = *(const short8*)&sK[buf][krow + ((4 + quad) ^ sw) * 8];
      #pragma unroll
      for (int qi = 0; qi < 2; qi++) {
        f32x4 st = __builtin_amdgcn_mfma_f32_16x16x32_bf16(a0, qf[qi][0], fzero, 0, 0, 0);
        st = __builtin_amdgcn_mfma_f32_16x16x32_bf16(a1, qf[qi][1], st, 0, 0, 0);
        float p0 = fexp2(st[0]), p1 = fexp2(st[1]);
        float p2 = fexp2(st[2]), p3 = fexp2(st[3]);
        pk[ki][qi][0] = packrn(p0, p1);
        pk[ki][qi][1] = packrn(p2, p3);
      }
    }

    #pragma unroll
    for (int ki = 0; ki < 4; ki++) {
      short4v bv[4];
      const int g = ((ki * 2 + (quad >> 1)) ^ sw) * 8 + (quad & 1) * 4;
      #pragma unroll
      for (int di = 0; di < 4; di++)
        bv[di] = *(const short4v*)&sV[buf][(di * 16 + l15) * 64 + g];
      #pragma unroll
      for (int qi = 0; qi < 2; qi++) {
        int2v t; t.x = (int)pk[ki][qi][0]; t.y = (int)pk[ki][qi][1];
        short4v aP = __builtin_bit_cast(short4v, t);
        oSum[qi] = mfma16(aP, onesv, oSum[qi]);
        #pragma unroll
        for (int di = 0; di < 4; di++)
          o[qi][di] = mfma16(aP, bv[di], o[qi][di]);
      }
    }
  }
#undef STAGE

  float linv[2][4];
  #pragma unroll
  for (int qi = 0; qi < 2; qi++)
    #pragma unroll
    for (int r = 0; r < 4; r++)
      linv[qi][r] = 1.0f / oSum[qi][r];

  #pragma unroll
  for (int qi = 0; qi < 2; qi++)
    #pragma unroll
    for (int di = 0; di < 4; di++)
      #pragma unroll
      for (int r = 0; r < 4; r++) {
        int row = q0 + wm + qi * 16 + quad * 4 + r;
        int col = h * HD + di * 16 + l15;
        O[(tokBase + row) * C + col] = f2bf(o[qi][di][r] * linv[qi][r]);
      }
}

extern "C" void kernel_launch(void* const* d_in, const int* in_sizes, int n_in,
                              void* d_out, int out_size, void* d_ws, size_t ws_size,
                              hipStream_t stream) {
  const float* x   = (const float*)d_in[0];
  const float* pos = (const float*)d_in[1];
  const float* nqg = (const float*)d_in[2];
  const float* nqb = (const float*)d_in[3];
  const float* nkg = (const float*)d_in[4];
  const float* nkb = (const float*)d_in[5];
  const float* nvg = (const float*)d_in[6];
  const float* nvb = (const float*)d_in[7];
  const float* ng  = (const float*)d_in[8];
  const float* nb  = (const float*)d_in[9];
  const float* wq  = (const float*)d_in[10];
  const float* bq  = (const float*)d_in[11];
  const float* wk  = (const float*)d_in[12];
  const float* bk  = (const float*)d_in[13];
  const float* wv  = (const float*)d_in[14];
  const float* bv  = (const float*)d_in[15];
  const float* wp  = (const float*)d_in[16];
  const float* bp  = (const float*)d_in[17];
  const float* w1  = (const float*)d_in[18];
  const float* b1  = (const float*)d_in[19];
  const float* w2  = (const float*)d_in[20];
  const float* b2  = (const float*)d_in[21];

  char* ws = (char*)d_ws;
  const size_t MB = 1u << 20;
  short* wqT  = (short*)(ws + 0 * MB);
  short* wkT  = (short*)(ws + 2 * MB);
  short* wvT  = (short*)(ws + 4 * MB);
  short* wpT  = (short*)(ws + 6 * MB);
  short* w1T  = (short*)(ws + 8 * MB);     // [HID][C]
  short* w2T  = (short*)(ws + 16 * MB);    // [C][HID]
  short* xq   = (short*)(ws + 24 * MB);
  short* xk   = (short*)(ws + 40 * MB);
  short* xv   = (short*)(ws + 56 * MB);
  short* Qm   = (short*)(ws + 72 * MB);
  short* Km   = (short*)(ws + 88 * MB);
  short* Vm   = (short*)(ws + 104 * MB);
  short* Vt   = (short*)(ws + 120 * MB);
  short* y1   = (short*)(ws + 72 * MB);    // overlays Q/K/V/Vt (dead after attn)
  short* Ob   = xk;                         // overlays xk (dead after K-proj)
  short* hln  = xq;                         // overlays xq (dead after Q-proj)
  float* hbuf = (float*)(ws + 136 * MB);
  (void)ws_size; (void)in_sizes; (void)n_in; (void)out_size;

  dim3 blk(256);
  k_transpose_w4<<<dim3(32, 32, 4), blk, 0, stream>>>(wq, wk, wv, wp, wqT, wkT, wvT, wpT);
  k_transpose_w<<<dim3(128, 32), blk, 0, stream>>>(w1, w1T, C, HID);
  k_transpose_w<<<dim3(32, 128), blk, 0, stream>>>(w2, w2T, HID, C);
  k_ln_qkv<<<dim3(MTOT), blk, 0, stream>>>(x, pos, nqg, nqb, nkg, nkb, nvg, nvb, xq, xk, xv);
  k_gemm_qkv<<<dim3(MTOT / 128, C / 128, 3), blk, 0, stream>>>(xq, xk, xv, wqT, wkT, wvT,
                                                               bq, bk, bv, Qm, Km, Vm);
  k_transpose_v<<<dim3(SEQ / 32, HD / 32, Bb * NH), blk, 0, stream>>>(Vm, Vt);
  k_attn<<<dim3(Bb * NH, SEQ / 128), blk, 0, stream>>>(Qm, Km, Vt, Ob);
  k_gemm_n64<2><<<dim3(MTOT / 128, C / 64), blk, 0, stream>>>(Ob, wpT, bp, x, hbuf, C, C);
  k_ln1<<<dim3(MTOT), blk, 0, stream>>>(hbuf, ng, nb, hln);
  k_gemm<1><<<dim3(MTOT / 128, HID / 128), blk, 0, stream>>>(hln, w1T, b1, nullptr, y1, HID, C);
  k_gemm_n64<2><<<dim3(MTOT / 128, C / 64), blk, 0, stream>>>(y1, w2T, b2, hbuf, (float*)d_out, C, HID);
}